// Round 13
// baseline (511.768 us; speedup 1.0000x reference)
//
#include <hip/hip_runtime.h>
#include <hip/hip_bf16.h>

#define TC    2049
#define DI    512
#define NS    128
#define XPN   288   // DT_RANK + 2*N_STATE = 32 + 256

typedef short bfx8 __attribute__((ext_vector_type(8)));
typedef float f32x4 __attribute__((ext_vector_type(4)));
typedef float f32x2 __attribute__((ext_vector_type(2)));

__device__ __forceinline__ float us2f(unsigned short u) {
    union { unsigned int i; float f; } v; v.i = ((unsigned int)u) << 16; return v.f;
}
__device__ __forceinline__ unsigned short f2bf(float f) {
    unsigned int u = __float_as_uint(f);
    u = (u + 0x7FFF + ((u >> 16) & 1)) >> 16;   // round-to-nearest-even
    return (unsigned short)u;
}
__device__ __forceinline__ float sigm(float x) { return 1.f / (1.f + __expf(-x)); }

#define L2E 1.4426950408889634f

// raw v_exp_f32 (args are always <= 0 here; native flush behavior is correct)
__device__ __forceinline__ float fexp2(float x) {
#if __has_builtin(__builtin_amdgcn_exp2f)
    return __builtin_amdgcn_exp2f(x);
#else
    return __expf(x * 0.6931471805599453f);
#endif
}

// ---------------- dtype sniffing: bf16 inputs (flag=0) vs f32 inputs (flag=1) -----
__global__ void detect_kernel(const unsigned short* __restrict__ x, int* __restrict__ flag) {
    __shared__ int cnt;
    int tid = threadIdx.x;
    if (tid == 0) cnt = 0;
    __syncthreads();
    unsigned short u = x[tid];
    int e = (u >> 7) & 0xFF;
    int insane = (u != 0 && (e < 97 || e > 157)) ? 1 : 0;
    atomicAdd(&cnt, insane);
    __syncthreads();
    if (tid == 0) *flag = (cnt >= 64) ? 1 : 0;
}

// ---------------- widen inputs to f32 in workspace (18 plain entries) ----------------
struct WD { const void* src; float* dst; int n; };
struct WDT { WD e[18]; };
__global__ __launch_bounds__(256) void widen_all_kernel(WDT tab, const int* __restrict__ flag) {
    WD d = tab.e[blockIdx.y];
    const int f = *flag;
    const int stride = gridDim.x * 256;
    int i = blockIdx.x * 256 + threadIdx.x;
    if (f) {
        const float* s = (const float*)d.src;
        for (; i < d.n; i += stride) d.dst[i] = s[i];
    } else {
        const unsigned short* s = (const unsigned short*)d.src;
        for (; i < d.n; i += stride) d.dst[i] = us2f(s[i]);
    }
}

// ---------------- x -> bf16 (identity copy for bf16 inputs) ----------------
__global__ __launch_bounds__(256) void x2bf_kernel(
    const void* __restrict__ src, unsigned short* __restrict__ dst, int n,
    const int* __restrict__ flag)
{
    int i = blockIdx.x * 256 + threadIdx.x;
    if (i >= n) return;
    dst[i] = (*flag) ? f2bf(((const float*)src)[i]) : ((const unsigned short*)src)[i];
}

// ---------------- GEMM weight prep: transpose + bf16, Wt[n][k] ----------------
__global__ __launch_bounds__(256) void wt_plain_kernel(
    const void* __restrict__ src, unsigned short* __restrict__ dst,
    int K, int N, const int* __restrict__ flag)
{
    int i = blockIdx.x * 256 + threadIdx.x;
    if (i >= K * N) return;
    int n = i / K, k = i - n * K;
    size_t si = (size_t)k * N + n;
    if (*flag) dst[i] = f2bf(((const float*)src)[si]);
    else       dst[i] = ((const unsigned short*)src)[si];
}

// ---------------- xproj weight prep: column-permute + transpose + bf16 -----------
__global__ __launch_bounds__(256) void wt_xproj_kernel(
    const void* __restrict__ src, unsigned short* __restrict__ dst,
    const int* __restrict__ flag)
{
    int i = blockIdx.x * 256 + threadIdx.x;   // 288*512 = 147456
    if (i >= 147456) return;
    int c = i >> 9, k = i & 511;
    int s;
    if (c < 32) s = c;
    else if (c < 160) { int q = c - 32;  s = 32  + (q >> 3) + ((q & 7) << 4); }
    else             { int q = c - 160; s = 160 + (q >> 3) + ((q & 7) << 4); }
    size_t si = (size_t)k * 288 + s;
    if (*flag) dst[i] = f2bf(((const float*)src)[si]);
    else       dst[i] = ((const unsigned short*)src)[si];
}

// ---------------- bf16-MFMA GEMM, 32x64 tile, K=64/iter (2x blocks/CU) -------------
// 4 waves: wave w computes rows (w&1)*16..+16, cols (w>>1)*32..+32 (2 acc tiles).
__global__ __launch_bounds__(256) void gemm_mfma_kernel(
    const void* __restrict__ Ain, int lda, long long sA,
    const unsigned short* __restrict__ Wt, int N, int K,
    const float* __restrict__ bias,
    void* __restrict__ Cout, int ldc, long long sC,
    int M, int act, int a_bf16, int c_bf16)
{
    __shared__ __align__(16) unsigned short As[32][72];   // [m][k0..63] bf16
    __shared__ __align__(16) unsigned short Bs[64][72];   // [n][k0..63] bf16
    const int tid = threadIdx.x;
    const int wave = tid >> 6, lane = tid & 63;
    const int bm = blockIdx.x * 32, bn = blockIdx.y * 64;
    const int col = lane & 15, quad = lane >> 4;
    const int rb = (wave & 1) * 16, cb = (wave >> 1) * 32;

    f32x4 acc[2] = {{0.f,0.f,0.f,0.f},{0.f,0.f,0.f,0.f}};

    const int ar = tid >> 3, ak = (tid & 7) << 3;   // 32 rows x 8 chunks of 8
    const int wn = tid & 63, wk = (tid >> 6) << 3;
    const bool wok = (bn + wn) < N;
    const unsigned short* wrow = Wt + (size_t)(bn + wn) * K;
    const int gm = bm + ar;
    const unsigned short* abf = (const unsigned short*)Ain + (size_t)blockIdx.z * sA
                                + (size_t)gm * lda;
    const float* af32 = (const float*)Ain + (size_t)blockIdx.z * sA + (size_t)gm * lda;

    for (int kt = 0; kt < K; kt += 64) {
        bfx8 a0 = {0,0,0,0,0,0,0,0};
        if (gm < M) {
            if (a_bf16) {
                a0 = *(const bfx8*)(abf + kt + ak);
            } else {
                const float* ap = af32 + kt + ak;
                float4 v0 = *(const float4*)ap;
                float4 v1 = *(const float4*)(ap + 4);
                a0[0]=(short)f2bf(v0.x); a0[1]=(short)f2bf(v0.y);
                a0[2]=(short)f2bf(v0.z); a0[3]=(short)f2bf(v0.w);
                a0[4]=(short)f2bf(v1.x); a0[5]=(short)f2bf(v1.y);
                a0[6]=(short)f2bf(v1.z); a0[7]=(short)f2bf(v1.w);
            }
        }
        bfx8 b0 = {0,0,0,0,0,0,0,0}, b1 = {0,0,0,0,0,0,0,0};
        if (wok) {
            b0 = *(const bfx8*)(wrow + kt + wk);
            b1 = *(const bfx8*)(wrow + kt + 32 + wk);
        }
        __syncthreads();
        *(bfx8*)&As[ar][ak] = a0;
        *(bfx8*)&Bs[wn][wk] = b0;
        *(bfx8*)&Bs[wn][wk + 32] = b1;
        __syncthreads();
        bfx8 af0 = *(const bfx8*)&As[rb + col][quad << 3];
        bfx8 af1 = *(const bfx8*)&As[rb + col][32 + (quad << 3)];
#pragma unroll
        for (int ct = 0; ct < 2; ++ct) {
            bfx8 bf0 = *(const bfx8*)&Bs[cb + ct * 16 + col][quad << 3];
            acc[ct] = __builtin_amdgcn_mfma_f32_16x16x32_bf16(af0, bf0, acc[ct], 0, 0, 0);
            bfx8 bf1 = *(const bfx8*)&Bs[cb + ct * 16 + col][32 + (quad << 3)];
            acc[ct] = __builtin_amdgcn_mfma_f32_16x16x32_bf16(af1, bf1, acc[ct], 0, 0, 0);
        }
    }
#pragma unroll
    for (int ct = 0; ct < 2; ++ct) {
        int gn = bn + cb + ct * 16 + col;
        if (gn >= N) continue;
        float bv = bias ? bias[gn] : 0.f;
#pragma unroll
        for (int r = 0; r < 4; ++r) {
            int gmo = bm + rb + quad * 4 + r;
            if (gmo < M) {
                float v = acc[ct][r] + bv;
                if (act == 1) v = fmaxf(v, 0.f);
                size_t co = (size_t)blockIdx.z * sC + (size_t)gmo * ldc + gn;
                if (c_bf16) ((unsigned short*)Cout)[co] = f2bf(v);
                else        ((float*)Cout)[co] = v;
            }
        }
    }
}

// ---------------- causal depthwise conv (K=4) + silu; optional fused z-silu --------
__global__ __launch_bounds__(256) void conv_silu_kernel(
    const float* __restrict__ xzbase, int ld, long long bstride,
    const float* __restrict__ conv_w, const float* __restrict__ conv_b,
    float* __restrict__ xs, int T, int rev_mode, float* __restrict__ zio)
{
    int idx = blockIdx.x * 256 + threadIdx.x;
    if (idx >= 2 * T * DI) return;
    int half = idx / (T * DI);
    int rem = idx - half * T * DI;
    int t = rem >> 9, d = rem & 511;
    const float* xzp = xzbase + (rev_mode ? 0 : (size_t)half * bstride);
    int rev = rev_mode ? half : 0;
    float acc = conv_b[d];
#pragma unroll
    for (int k = 0; k < 4; ++k) {
        int tt = t - 3 + k;
        if (tt >= 0) {
            int g = rev ? (T - 1 - tt) : tt;
            acc += conv_w[d * 4 + k] * xzp[(size_t)g * ld + d];
        }
    }
    xs[idx] = acc * sigm(acc);
    // fused in-place silu on z columns (one thread per (t,d): half==0 only)
    if (zio && half == 0) {
        float* p = zio + (size_t)t * 1024 + 512 + d;
        float z = *p;
        *p = z * sigm(z);
    }
}

// ---------------- dt projection (K=32) + softplus ----------------
__global__ __launch_bounds__(256) void dt_kernel(
    const float* __restrict__ xdbl, const float* __restrict__ dt_w,
    const float* __restrict__ dt_b, float* __restrict__ dtout, int T)
{
    int idx = blockIdx.x * 256 + threadIdx.x;
    if (idx >= 2 * T * DI) return;
    int half = idx / (T * DI);
    int rem = idx - half * T * DI;
    int t = rem >> 9, j = rem & 511;
    const float* a = xdbl + (size_t)half * T * XPN + (size_t)t * XPN;
    float acc = dt_b[j];
#pragma unroll
    for (int k = 0; k < 32; ++k) acc += a[k] * dt_w[k * DI + j];
    dtout[idx] = (acc > 20.f) ? acc : log1pf(__expf(acc));
}

#define TT 16
#define RS1 196      // part1 LDS row stride (dwords): 16 lanes x 12 + pad
#define RS2 392      // emit LDS row stride: B seg at 0, C seg at +196

// ---------------- chunked scan pass 1 (LDS-staged, bank-spread layout) -------------
__global__ __launch_bounds__(256) void scan_part1_kernel(
    const float* __restrict__ dt, const float* __restrict__ xdbl,
    const float* __restrict__ xs, const float* __restrict__ A_log,
    float* __restrict__ Sarr, float* __restrict__ H, int T, int NC, int LC)
{
    __shared__ __align__(16) float xb[TT][RS1];
    __shared__ float sdt[TT][16], sxs[TT][16];
    int b2 = blockIdx.x;
    int c = b2 % NC;
    int dpq = b2 / NC;
    int tid = threadIdx.x;
    int w = tid >> 6, lane = tid & 63;
    int sub = lane >> 4, l = lane & 15;
    int jb = w * 4 + sub;                 // block-local d index 0..15
    int hd = dpq * 16 + jb;
    int d = hd & 511;
    int half = (dpq * 16) >> 9;
    int d0 = (dpq * 16) & 511;
    f32x2 a2[4];
#pragma unroll
    for (int q = 0; q < 4; ++q) {
        a2[q][0] = -__expf(A_log[d * NS + 32 * q + l])      * L2E;   // n = l + 16*(2q)
        a2[q][1] = -__expf(A_log[d * NS + 32 * q + 16 + l]) * L2E;   // n = l + 16*(2q+1)
    }
    int t0 = c * LC, t1 = min(T, t0 + LC);
    const size_t dbase = (size_t)half * T * DI + d0;
    const float* rowb = xdbl + (size_t)half * T * XPN + 32;
    float S = 0.f;
    f32x2 h2[4] = {{0.f,0.f},{0.f,0.f},{0.f,0.f},{0.f,0.f}};
    int st = tid >> 4, sj = tid & 15;     // staging coords for dt/xs
    const int lo = 12 * l;
    for (int tt = t0; tt < t1; tt += TT) {
        __syncthreads();
        // stage B rows: 16t x 32 float4; dst chunked 12-dword per lane.
        // Over-reads past t1 (cross tail) stay inside d_ws and are never consumed.
#pragma unroll
        for (int q = 0; q < 2; ++q) {
            int fi = q * 256 + tid;
            int t = fi >> 5, g = fi & 31;
            float4 v = *(const float4*)(rowb + (size_t)(tt + t) * XPN + g * 4);
            *(float4*)&xb[t][12 * (g >> 1) + 4 * (g & 1)] = v;
        }
        {   // stage dt/xs scalars: 16t x 16d
            size_t g = dbase + (size_t)(tt + st) * DI + sj;
            sdt[st][sj] = dt[g];
            sxs[st][sj] = xs[g];
        }
        __syncthreads();
        int nt = min(TT, t1 - tt);
        int k = 0;
        for (; k + 2 <= nt; k += 2) {
            float dva = sdt[k][jb],     xva = sxs[k][jb];
            float dvb = sdt[k + 1][jb], xvb = sxs[k + 1][jb];
            float4 v0 = *(const float4*)&xb[k][lo];
            float4 v1 = *(const float4*)&xb[k][lo + 4];
            float4 w0 = *(const float4*)&xb[k + 1][lo];
            float4 w1 = *(const float4*)&xb[k + 1][lo + 4];
            f32x2 Ba[4] = {{v0.x,v0.y},{v0.z,v0.w},{v1.x,v1.y},{v1.z,v1.w}};
            f32x2 Bb[4] = {{w0.x,w0.y},{w0.z,w0.w},{w1.x,w1.y},{w1.z,w1.w}};
            float ua = dva * xva, ub = dvb * xvb;
            S += dva + dvb;
            f32x2 ua2 = {ua, ua}, ub2 = {ub, ub};
            f32x2 dva2 = {dva, dva}, dvb2 = {dvb, dvb};
#pragma unroll
            for (int q = 0; q < 4; ++q) {
                f32x2 ga = dva2 * a2[q];
                f32x2 ea; ea[0] = fexp2(ga[0]); ea[1] = fexp2(ga[1]);
                h2[q] = h2[q] * ea + ua2 * Ba[q];
                f32x2 gb = dvb2 * a2[q];
                f32x2 eb; eb[0] = fexp2(gb[0]); eb[1] = fexp2(gb[1]);
                h2[q] = h2[q] * eb + ub2 * Bb[q];
            }
        }
        if (k < nt) {
            float dv = sdt[k][jb], xv = sxs[k][jb];
            float4 v0 = *(const float4*)&xb[k][lo];
            float4 v1 = *(const float4*)&xb[k][lo + 4];
            f32x2 Bv[4] = {{v0.x,v0.y},{v0.z,v0.w},{v1.x,v1.y},{v1.z,v1.w}};
            float u = dv * xv;
            S += dv;
            f32x2 u2 = {u, u}, dv2 = {dv, dv};
#pragma unroll
            for (int q = 0; q < 4; ++q) {
                f32x2 g = dv2 * a2[q];
                f32x2 e; e[0] = fexp2(g[0]); e[1] = fexp2(g[1]);
                h2[q] = h2[q] * e + u2 * Bv[q];
            }
        }
    }
    size_t base = ((size_t)hd * NC + c) * 128 + l;
#pragma unroll
    for (int q = 0; q < 4; ++q) {
        H[base + 32 * q]      = h2[q][0];
        H[base + 32 * q + 16] = h2[q][1];
    }
    if (l == 0) Sarr[(size_t)hd * NC + c] = S;
}

// ---------------- chunked scan pass 2: serial combine (in-place H -> h_start) ------
__global__ __launch_bounds__(128) void scan_combine_kernel(
    const float* __restrict__ Sarr, float* __restrict__ H,
    const float* __restrict__ A_log, float* __restrict__ Hfinal, int NC)
{
    int hd = blockIdx.x;
    int d = hd & 511;
    int n = threadIdx.x;
    float a = -__expf(A_log[d * NS + n]) * L2E;
    size_t base = (size_t)hd * NC * 128 + n;
    float h = 0.f;
    for (int c = 0; c < NC; ++c) {
        size_t off = base + (size_t)c * 128;
        float p = fexp2(a * Sarr[(size_t)hd * NC + c]);
        float hh = H[off];
        H[off] = h;                // h_start for chunk c (exclusive prefix)
        h = p * h + hh;
    }
    if (Hfinal) Hfinal[(size_t)hd * 128 + n] = h;
}

// ---------------- chunked scan pass 3: LDS-staged replay + emit gated y (bf16) ------
__global__ __launch_bounds__(256) void scan_emit_kernel(
    const float* __restrict__ dt, const float* __restrict__ xdbl,
    const float* __restrict__ xs, const float* __restrict__ xz,
    const float* __restrict__ A_log, const float* __restrict__ Hstart,
    const float* __restrict__ Dp,
    unsigned short* __restrict__ y, int T, int NC, int LC)
{
    __shared__ __align__(16) float xb[TT][RS2];   // B seg at 0, C seg at +196
    __shared__ float sdt[TT][16], sxs[TT][16], sz[TT][16];
    int b2 = blockIdx.x;
    int c = b2 % NC;
    int dpq = b2 / NC;
    int tid = threadIdx.x;
    int w = tid >> 6, lane = tid & 63;
    int sub = lane >> 4, l = lane & 15;
    int jb = w * 4 + sub;
    int hd = dpq * 16 + jb;
    int d = hd & 511;
    int half = (dpq * 16) >> 9;
    int d0 = (dpq * 16) & 511;
    f32x2 a2[4];
#pragma unroll
    for (int q = 0; q < 4; ++q) {
        a2[q][0] = -__expf(A_log[d * NS + 32 * q + l])      * L2E;
        a2[q][1] = -__expf(A_log[d * NS + 32 * q + 16 + l]) * L2E;
    }
    const float Dv = Dp[d];
    size_t base = ((size_t)hd * NC + c) * 128 + l;
    f32x2 h2[4];
#pragma unroll
    for (int q = 0; q < 4; ++q) {
        h2[q][0] = Hstart[base + 32 * q];
        h2[q][1] = Hstart[base + 32 * q + 16];
    }
    int t0 = c * LC, t1 = min(T, t0 + LC);
    const size_t dbase = (size_t)half * T * DI + d0;
    const float* rowb = xdbl + (size_t)half * T * XPN + 32;
    int st = tid >> 4, sj = tid & 15;
    size_t ybase = (size_t)half * T * DI + d;
    const int lo = 12 * l;
    for (int tt = t0; tt < t1; tt += TT) {
        __syncthreads();
        // stage B+C rows: 16t x 64 float4; per-seg chunked 12-dword per lane.
#pragma unroll
        for (int q = 0; q < 4; ++q) {
            int fi = q * 256 + tid;
            int t = fi >> 6, g = fi & 63;
            int seg = g >> 5, gl = g & 31;
            float4 v = *(const float4*)(rowb + (size_t)(tt + t) * XPN + g * 4);
            *(float4*)&xb[t][seg * 196 + 12 * (gl >> 1) + 4 * (gl & 1)] = v;
        }
        {   // stage dt/xs/silu(z) scalars
            size_t g = dbase + (size_t)(tt + st) * DI + sj;
            sdt[st][sj] = dt[g];
            sxs[st][sj] = xs[g];
            int tg = half ? (T - 1 - (tt + st)) : (tt + st);
            sz[st][sj] = xz[(size_t)tg * 1024 + 512 + d0 + sj];
        }
        __syncthreads();
        int nt = min(TT, t1 - tt);
        for (int k = 0; k + 2 <= nt; k += 2) {
            float dva = sdt[k][jb],     xva = sxs[k][jb];
            float dvb = sdt[k + 1][jb], xvb = sxs[k + 1][jb];
            float ga = sz[k][jb], gb = sz[k + 1][jb];
            float4 v0 = *(const float4*)&xb[k][lo];
            float4 v1 = *(const float4*)&xb[k][lo + 4];
            float4 c0 = *(const float4*)&xb[k][196 + lo];
            float4 c1 = *(const float4*)&xb[k][196 + lo + 4];
            float4 w0 = *(const float4*)&xb[k + 1][lo];
            float4 w1 = *(const float4*)&xb[k + 1][lo + 4];
            float4 e0 = *(const float4*)&xb[k + 1][196 + lo];
            float4 e1 = *(const float4*)&xb[k + 1][196 + lo + 4];
            f32x2 Ba[4] = {{v0.x,v0.y},{v0.z,v0.w},{v1.x,v1.y},{v1.z,v1.w}};
            f32x2 Ca[4] = {{c0.x,c0.y},{c0.z,c0.w},{c1.x,c1.y},{c1.z,c1.w}};
            f32x2 Bb[4] = {{w0.x,w0.y},{w0.z,w0.w},{w1.x,w1.y},{w1.z,w1.w}};
            f32x2 Cb[4] = {{e0.x,e0.y},{e0.z,e0.w},{e1.x,e1.y},{e1.z,e1.w}};
            float ua = dva * xva, ub = dvb * xvb;
            f32x2 ua2 = {ua, ua}, ub2 = {ub, ub};
            f32x2 dva2 = {dva, dva}, dvb2 = {dvb, dvb};
            f32x2 pa2 = {0.f, 0.f}, pb2 = {0.f, 0.f};
#pragma unroll
            for (int q = 0; q < 4; ++q) {
                f32x2 gaa = dva2 * a2[q];
                f32x2 ea; ea[0] = fexp2(gaa[0]); ea[1] = fexp2(gaa[1]);
                h2[q] = h2[q] * ea + ua2 * Ba[q];
                pa2 += h2[q] * Ca[q];
            }
#pragma unroll
            for (int q = 0; q < 4; ++q) {
                f32x2 gbb = dvb2 * a2[q];
                f32x2 eb; eb[0] = fexp2(gbb[0]); eb[1] = fexp2(gbb[1]);
                h2[q] = h2[q] * eb + ub2 * Bb[q];
                pb2 += h2[q] * Cb[q];
            }
            float pa = pa2[0] + pa2[1], pb = pb2[0] + pb2[1];
            pa += __shfl_xor(pa, 1, 64);  pb += __shfl_xor(pb, 1, 64);
            pa += __shfl_xor(pa, 2, 64);  pb += __shfl_xor(pb, 2, 64);
            pa += __shfl_xor(pa, 4, 64);  pb += __shfl_xor(pb, 4, 64);
            pa += __shfl_xor(pa, 8, 64);  pb += __shfl_xor(pb, 8, 64);
            if (l == 0) {
                y[ybase + (size_t)(tt + k) * DI]     = f2bf((pa + xva * Dv) * ga);
                y[ybase + (size_t)(tt + k + 1) * DI] = f2bf((pb + xvb * Dv) * gb);
            }
        }
    }
}

// ---------------- cross: last-step readout (permuted C layout) ----------------
__global__ __launch_bounds__(64) void cross_readout_kernel(
    const float* __restrict__ Hfinal, const float* __restrict__ xdbl,
    const float* __restrict__ xs, const float* __restrict__ xz,
    const float* __restrict__ Dp, float* __restrict__ ylast, int T)
{
    int hd = blockIdx.x;
    int half = hd >> 9, d = hd & 511;
    int lane = threadIdx.x;
    xdbl += (size_t)half * T * XPN;
    xs   += (size_t)half * T * DI;
    xz   += (size_t)half * T * 1024;
    float h0 = Hfinal[(size_t)hd * 128 + lane];          // state n = lane
    float h1 = Hfinal[(size_t)hd * 128 + 64 + lane];     // state n = 64+lane
    const float* xl = xdbl + (size_t)(T - 1) * XPN;
    int pos = 160 + (lane & 15) * 8 + (lane >> 4);
    float C0 = xl[pos];            // n = lane
    float C1 = xl[pos + 4];        // n = 64+lane
    float p = h0 * C0 + h1 * C1;
#pragma unroll
    for (int off = 32; off > 0; off >>= 1) p += __shfl_down(p, off, 64);
    if (lane == 0) {
        float xlast = xs[(size_t)(T - 1) * DI + d];
        float zl = xz[(size_t)(T - 1) * 1024 + 512 + d];
        ylast[half * DI + d] = (p + xlast * Dp[d]) * (zl * sigm(zl));
    }
}

// ---------------- row softmax + scatter into both cross sequences (bf16 SEQ) -------
__global__ __launch_bounds__(256) void softmax_scatter_kernel(
    const float* __restrict__ yo, unsigned short* __restrict__ seq, int T)
{
    __shared__ float sm[4];
    const int t = blockIdx.x, half = blockIdx.y, tid = threadIdx.x;
    const float* row = yo + (size_t)half * T * DI + (size_t)t * DI;
    float v0 = row[tid], v1 = row[tid + 256];
    float m = fmaxf(v0, v1);
#pragma unroll
    for (int o = 32; o > 0; o >>= 1) m = fmaxf(m, __shfl_xor(m, o, 64));
    if ((tid & 63) == 0) sm[tid >> 6] = m;
    __syncthreads();
    m = fmaxf(fmaxf(sm[0], sm[1]), fmaxf(sm[2], sm[3]));
    __syncthreads();
    float e0 = __expf(v0 - m), e1 = __expf(v1 - m);
    float s = e0 + e1;
#pragma unroll
    for (int o = 32; o > 0; o >>= 1) s += __shfl_xor(s, o, 64);
    if ((tid & 63) == 0) sm[tid >> 6] = s;
    __syncthreads();
    s = sm[0] + sm[1] + sm[2] + sm[3];
    float inv = 1.f / s;
    unsigned short b0 = f2bf(e0 * inv), b1 = f2bf(e1 * inv);
    unsigned short* seq_fi = seq;
    unsigned short* seq_if = seq + (size_t)TC * 1024;
    if (half == 0) {
        unsigned short* d1 = seq_fi + (size_t)t * 1024;
        unsigned short* d2 = seq_if + (size_t)t * 1024 + 512;
        d1[tid] = b0; d1[tid + 256] = b1;
        d2[tid] = b0; d2[tid + 256] = b1;
    } else {
        int tg = T - 1 - t;
        unsigned short* d1 = seq_fi + (size_t)tg * 1024 + 512;
        unsigned short* d2 = seq_if + (size_t)tg * 1024;
        d1[tid] = b0; d1[tid + 256] = b1;
        d2[tid] = b0; d2[tid + 256] = b1;
    }
}

// ---------------- cls-token rows of the two sequences (bf16) ----------------
__global__ __launch_bounds__(256) void cls_rows_kernel(
    const float* __restrict__ cls1, const float* __restrict__ cls2,
    unsigned short* __restrict__ seq)
{
    int i = blockIdx.x * 256 + threadIdx.x;   // 0..2047
    if (i < 1024)
        seq[(size_t)(TC - 1) * 1024 + i] = f2bf(cls1[i]);
    else
        seq[(size_t)TC * 1024 + (size_t)(TC - 1) * 1024 + (i - 1024)] = f2bf(cls2[i - 1024]);
}

// ---------------- vec [512] @ out_w [512,512] -> [512] ----------------
__global__ __launch_bounds__(256) void vecmat_kernel(
    const float* __restrict__ ylast, const float* __restrict__ Wout,
    float* __restrict__ olast)
{
    int half = blockIdx.y;
    int j = blockIdx.x * 256 + threadIdx.x;
    const float* v = ylast + half * DI;
    float acc = 0.f;
    for (int k = 0; k < DI; ++k) acc += v[k] * Wout[k * DI + j];
    olast[half * DI + j] = acc;
}

// ---------------- final classifier -> f32 [2] ----------------
__global__ __launch_bounds__(256) void final_kernel(
    const float* __restrict__ ol, const float* __restrict__ cw,
    const float* __restrict__ cb, float* __restrict__ out)
{
    __shared__ float s0[4], s1[4];
    int tid = threadIdx.x;
    float a0 = 0.f, a1 = 0.f;
    for (int j = tid; j < 1024; j += 256) {
        float v = ol[j];
        a0 += v * cw[2 * j];
        a1 += v * cw[2 * j + 1];
    }
#pragma unroll
    for (int o = 32; o > 0; o >>= 1) { a0 += __shfl_xor(a0, o, 64); a1 += __shfl_xor(a1, o, 64); }
    if ((tid & 63) == 0) { s0[tid >> 6] = a0; s1[tid >> 6] = a1; }
    __syncthreads();
    if (tid == 0) {
        out[0] = s0[0] + s0[1] + s0[2] + s0[3] + cb[0];
        out[1] = s1[0] + s1[1] + s1[2] + s1[3] + cb[1];
    }
}

extern "C" void kernel_launch(void* const* d_in, const int* in_sizes, int n_in,
                              void* d_out, int out_size, void* d_ws, size_t ws_size,
                              hipStream_t stream)
{
    float* out = (float*)d_out;
    float* ws = (float*)d_ws;

    // ---- input-order resolution via in_sizes (dict vs signature order) ----
    static const int sig_map[25] = {0,1,2,3,4,23,24,5,6,7,8,9,10,11,12,13,
                                    14,15,16,17,18,19,20,21,22};
    int idx[25];
    bool dict_order = (n_in >= 7 && in_sizes[6] == 2);
    for (int i = 0; i < 25; ++i) idx[i] = dict_order ? i : sig_map[i];

    // ---- aliased workspace layout (f32 elements) ----
    const size_t A0 = 0;         // x(bf16) -> dt_simple -> yo -> XSC         (2,098,176)
    const size_t B0 = 2098176;   // f(bf16) / S_S -> XDC                      (1,180,224)
    const size_t C0 = 3278400;   // XZS / XZC (XZC spans ..7,474,752)         (2,097,152)
    const size_t D0 = 5375552;   // XS                                        (2,097,152)
    const size_t E0 = 7472704;   // XDBL                                      (1,179,648)
    const size_t F0 = 8652352;   // y(bf16) / YS                              (2,097,152)
    const size_t G0 = 10749504;  // H_S (NC=32, 4,194,304) -> SEQ(bf16)       (4,196,352)
    const size_t YL0 = 14945856; // 1024
    const size_t OL0 = 14946880; // 1024
    const size_t DT_S = A0;
    const size_t S_S  = B0 + 524288;     // after bf16 f (f = 1M ushorts = 524,288 fl)
    const size_t H_S  = G0;              // 1024*32*128 = 4,194,304
    const size_t DT_C = 7474752;
    const size_t H_C  = 9572928;         // 1024*33*128 = 4,325,376 -> ends 13,898,304
    const size_t S_C  = 13898304;        // 1024*33 = 33,792
    const size_t HFIN = 14029376;        // 131,072
    size_t o = 14947904;
    const size_t P_FEATW = o; o += 524288;   // bf16 Wt[512][1024]
    const size_t P_FEATB = o; o += 512;
    const size_t P_CLS1  = o; o += 1024;
    const size_t P_CLS2  = o; o += 1024;
    const size_t P_CLSW  = o; o += 2048;
    const size_t P_CLSB  = o; o += 4;
    const size_t P_MINW  = o; o += 524288;   // bf16 Wt[1024][512]
    const size_t P_MCW   = o; o += 2048;
    const size_t P_MCB   = o; o += 512;
    const size_t P_MXP   = o; o += 147456;   // bf16 Wt[288][512]
    const size_t P_MDTW  = o; o += 16384;
    const size_t P_MDTB  = o; o += 512;
    const size_t P_MAL   = o; o += 65536;
    const size_t P_MD    = o; o += 512;
    const size_t P_MOW   = o; o += 262144;   // bf16 Wt[512][512]
    const size_t P_CINW  = o; o += 1048576;  // bf16 Wt[1024][1024]
    const size_t P_CCW   = o; o += 2048;
    const size_t P_CCB   = o; o += 512;
    const size_t P_CXP   = o; o += 147456;   // bf16 Wt[288][512]
    const size_t P_CDTW  = o; o += 16384;
    const size_t P_CDTB  = o; o += 512;
    const size_t P_CAL   = o; o += 65536;
    const size_t P_CD    = o; o += 512;
    const size_t P_COW   = o; o += 262144;
    const size_t OFF_FLAG = o;               // 1 int

    int* flagp = (int*)(ws + OFF_FLAG);
    unsigned short* XB   = (unsigned short*)(ws + A0);
    unsigned short* FB   = (unsigned short*)(ws + B0);
    unsigned short* YB   = (unsigned short*)(ws + F0);
    unsigned short* SEQB = (unsigned short*)(ws + G0);
    unsigned short* WT_FEATW = (unsigned short*)(ws + P_FEATW);
    unsigned short* WT_MINW  = (unsigned short*)(ws + P_MINW);
    unsigned short* WT_MXP   = (unsigned short*)(ws + P_MXP);
    unsigned short* WT_MOW   = (unsigned short*)(ws + P_MOW);
    unsigned short* WT_CINW  = (unsigned short*)(ws + P_CINW);
    unsigned short* WT_CXP   = (unsigned short*)(ws + P_CXP);

    // 0) detect input dtype
    detect_kernel<<<1, 256, 0, stream>>>((const unsigned short*)d_in[idx[0]], flagp);

    // 1) widen non-GEMM inputs (18 plain) + x->bf16 + 6 GEMM weights (bf16, transposed)
    WDT tab;
    const int lg[18]  = {2,3,4,5,6,8,9,11,12,13,14,17,18,20,21,22,23,24};
    const int nsl[25] = {2097152, 524288, 512, 1024, 1024, 2048, 2,
                         524288, 2048, 512, 147456, 16384, 512, 65536, 512, 262144,
                         1048576, 2048, 512, 147456, 16384, 512, 65536, 512, 262144};
    float* dstl[25] = {
        nullptr, nullptr, ws + P_FEATB, ws + P_CLS1, ws + P_CLS2,
        ws + P_CLSW, ws + P_CLSB,
        nullptr, ws + P_MCW, ws + P_MCB, nullptr, ws + P_MDTW, ws + P_MDTB,
        ws + P_MAL, ws + P_MD, nullptr,
        nullptr, ws + P_CCW, ws + P_CCB, nullptr, ws + P_CDTW, ws + P_CDTB,
        ws + P_CAL, ws + P_CD, ws + P_COW};
    for (int i = 0; i < 18; ++i) {
        int s = lg[i];
        tab.e[i].src = d_in[idx[s]];
        tab.e[i].dst = dstl[s];
        tab.e[i].n = nsl[s];
    }
    widen_all_kernel<<<dim3(128, 18), 256, 0, stream>>>(tab, flagp);
    x2bf_kernel<<<8192, 256, 0, stream>>>(d_in[idx[0]], XB, 2097152, flagp);
    wt_plain_kernel<<<2048, 256, 0, stream>>>(d_in[idx[1]],  WT_FEATW, 1024, 512,  flagp);
    wt_plain_kernel<<<2048, 256, 0, stream>>>(d_in[idx[7]],  WT_MINW,  512,  1024, flagp);
    wt_plain_kernel<<<1024, 256, 0, stream>>>(d_in[idx[15]], WT_MOW,   512,  512,  flagp);
    wt_plain_kernel<<<4096, 256, 0, stream>>>(d_in[idx[16]], WT_CINW,  1024, 1024, flagp);
    wt_xproj_kernel<<<576, 256, 0, stream>>>(d_in[idx[10]], WT_MXP, flagp);
    wt_xproj_kernel<<<576, 256, 0, stream>>>(d_in[idx[19]], WT_CXP, flagp);

    // 2) f = relu(x @ feat_w + feat_b)        A(bf16) -> B(bf16)
    gemm_mfma_kernel<<<dim3(64, 8, 1), 256, 0, stream>>>(XB, 1024, 0, WT_FEATW, 512, 1024,
                                                         ws + P_FEATB, FB, 512, 0,
                                                         2048, 1, 1, 1);
    // 3) xz = f @ m_in_w                      B(bf16) -> C(f32)
    gemm_mfma_kernel<<<dim3(64, 16, 1), 256, 0, stream>>>(FB, 512, 0, WT_MINW, 1024, 512,
                                                          nullptr, ws + C0, 1024, 0,
                                                          2048, 0, 1, 0);
    // 4) conv+silu both dirs + fused in-place z-silu    C -> D (+C z-cols)
    conv_silu_kernel<<<8192, 256, 0, stream>>>(ws + C0, 1024, 0, ws + P_MCW, ws + P_MCB,
                                               ws + D0, 2048, 1, ws + C0);
    // 5) x_dbl = xs @ m_xproj_w (permuted)    D(f32) -> E(f32)
    gemm_mfma_kernel<<<dim3(64, 5, 2), 256, 0, stream>>>(ws + D0, 512, 2048LL * 512, WT_MXP,
                                                         288, 512, nullptr, ws + E0, 288,
                                                         2048LL * 288, 2048, 0, 0, 0);
    // 5b) dt = softplus(x_dbl[:, :32] @ dt_w + dt_b)   E -> DT_S (A)
    dt_kernel<<<8192, 256, 0, stream>>>(ws + E0, ws + P_MDTW, ws + P_MDTB, ws + DT_S, 2048);
    // 6) chunked scan: T=2048, 32 chunks x 64 (64 dpq x 32 c = 2048 blocks)
    scan_part1_kernel<<<2048, 256, 0, stream>>>(ws + DT_S, ws + E0, ws + D0, ws + P_MAL,
                                                ws + S_S, ws + H_S, 2048, 32, 64);
    scan_combine_kernel<<<1024, 128, 0, stream>>>(ws + S_S, ws + H_S, ws + P_MAL, nullptr, 32);
    // 6b) emit with fused gating, bf16 y out
    scan_emit_kernel<<<2048, 256, 0, stream>>>(ws + DT_S, ws + E0, ws + D0, ws + C0,
                                               ws + P_MAL, ws + H_S, ws + P_MD,
                                               YB, 2048, 32, 64);
    // 7) yo = y @ m_out_w                     F(bf16) -> A(f32 yo)
    gemm_mfma_kernel<<<dim3(64, 8, 2), 256, 0, stream>>>(YB, 512, 2048LL * 512, WT_MOW,
                                                         512, 512, nullptr, ws + A0, 512,
                                                         2048LL * 512, 2048, 0, 1, 0);
    // 8) cls-token rows into SEQ (bf16)       P -> G
    cls_rows_kernel<<<8, 256, 0, stream>>>(ws + P_CLS1, ws + P_CLS2, SEQB);
    // 9) softmax + scatter (bf16 SEQ)         A -> G
    softmax_scatter_kernel<<<dim3(2048, 2), 256, 0, stream>>>(ws + A0, SEQB, 2048);
    // 10) cross in-proj                       G(bf16) -> C(f32 XZC)
    gemm_mfma_kernel<<<dim3(65, 16, 2), 256, 0, stream>>>(SEQB, 1024, 2049LL * 1024, WT_CINW,
                                                          1024, 1024, nullptr, ws + C0, 1024,
                                                          2049LL * 1024, 2049, 0, 1, 0);
    // 11) cross conv+silu (no fused z)        C -> A (XSC)
    conv_silu_kernel<<<8196, 256, 0, stream>>>(ws + C0, 1024, 2049LL * 1024, ws + P_CCW,
                                               ws + P_CCB, ws + A0, 2049, 0, nullptr);
    // 12) cross x_dbl (permuted)              A(f32) -> B(f32 XDC)
    gemm_mfma_kernel<<<dim3(65, 5, 2), 256, 0, stream>>>(ws + A0, 512, 2049LL * 512, WT_CXP,
                                                         288, 512, nullptr, ws + B0, 288,
                                                         2049LL * 288, 2049, 0, 0, 0);
    // 12b) cross dt                           B -> DT_C
    dt_kernel<<<8196, 256, 0, stream>>>(ws + B0, ws + P_CDTW, ws + P_CDTB, ws + DT_C, 2049);
    // 13) cross chunked scan: T=2049, 33 chunks x 64 (64 dpq x 33 c = 2112 blocks)
    scan_part1_kernel<<<2112, 256, 0, stream>>>(ws + DT_C, ws + B0, ws + A0, ws + P_CAL,
                                                ws + S_C, ws + H_C, 2049, 33, 64);
    scan_combine_kernel<<<1024, 128, 0, stream>>>(ws + S_C, ws + H_C, ws + P_CAL, ws + HFIN, 33);
    cross_readout_kernel<<<1024, 64, 0, stream>>>(ws + HFIN, ws + B0, ws + A0, ws + C0,
                                                  ws + P_CD, ws + YL0, 2049);
    // 14) out-projection of last rows         YL -> OL
    vecmat_kernel<<<dim3(2, 2), 256, 0, stream>>>(ws + YL0, ws + P_COW, ws + OL0);
    // 15) classifier                          OL -> out (f32)
    final_kernel<<<1, 256, 0, stream>>>(ws + OL0, ws + P_CLSW, ws + P_CLSB, out);
}

// Round 14
// 506.040 us; speedup vs baseline: 1.0113x; 1.0113x over previous
//
#include <hip/hip_runtime.h>
#include <hip/hip_bf16.h>

#define TC    2049
#define DI    512
#define NS    128
#define XPN   288   // DT_RANK + 2*N_STATE = 32 + 256

typedef short bfx8 __attribute__((ext_vector_type(8)));
typedef float f32x4 __attribute__((ext_vector_type(4)));
typedef float f32x2 __attribute__((ext_vector_type(2)));

__device__ __forceinline__ float us2f(unsigned short u) {
    union { unsigned int i; float f; } v; v.i = ((unsigned int)u) << 16; return v.f;
}
__device__ __forceinline__ unsigned short f2bf(float f) {
    unsigned int u = __float_as_uint(f);
    u = (u + 0x7FFF + ((u >> 16) & 1)) >> 16;   // round-to-nearest-even
    return (unsigned short)u;
}
__device__ __forceinline__ float sigm(float x) { return 1.f / (1.f + __expf(-x)); }

#define L2E 1.4426950408889634f

// raw v_exp_f32 (args are always <= 0 here; native flush behavior is correct)
__device__ __forceinline__ float fexp2(float x) {
#if __has_builtin(__builtin_amdgcn_exp2f)
    return __builtin_amdgcn_exp2f(x);
#else
    return __expf(x * 0.6931471805599453f);
#endif
}

// ---------------- dtype sniffing: bf16 inputs (flag=0) vs f32 inputs (flag=1) -----
__global__ void detect_kernel(const unsigned short* __restrict__ x, int* __restrict__ flag) {
    __shared__ int cnt;
    int tid = threadIdx.x;
    if (tid == 0) cnt = 0;
    __syncthreads();
    unsigned short u = x[tid];
    int e = (u >> 7) & 0xFF;
    int insane = (u != 0 && (e < 97 || e > 157)) ? 1 : 0;
    atomicAdd(&cnt, insane);
    __syncthreads();
    if (tid == 0) *flag = (cnt >= 64) ? 1 : 0;
}

// ---------------- widen inputs to f32 in workspace (18 plain entries) ----------------
struct WD { const void* src; float* dst; int n; };
struct WDT { WD e[18]; };
__global__ __launch_bounds__(256) void widen_all_kernel(WDT tab, const int* __restrict__ flag) {
    WD d = tab.e[blockIdx.y];
    const int f = *flag;
    const int stride = gridDim.x * 256;
    int i = blockIdx.x * 256 + threadIdx.x;
    if (f) {
        const float* s = (const float*)d.src;
        for (; i < d.n; i += stride) d.dst[i] = s[i];
    } else {
        const unsigned short* s = (const unsigned short*)d.src;
        for (; i < d.n; i += stride) d.dst[i] = us2f(s[i]);
    }
}

// ---------------- x -> bf16 (identity copy for bf16 inputs) ----------------
__global__ __launch_bounds__(256) void x2bf_kernel(
    const void* __restrict__ src, unsigned short* __restrict__ dst, int n,
    const int* __restrict__ flag)
{
    int i = blockIdx.x * 256 + threadIdx.x;
    if (i >= n) return;
    dst[i] = (*flag) ? f2bf(((const float*)src)[i]) : ((const unsigned short*)src)[i];
}

// ---------------- GEMM weight prep: transpose + bf16, Wt[n][k] ----------------
__global__ __launch_bounds__(256) void wt_plain_kernel(
    const void* __restrict__ src, unsigned short* __restrict__ dst,
    int K, int N, const int* __restrict__ flag)
{
    int i = blockIdx.x * 256 + threadIdx.x;
    if (i >= K * N) return;
    int n = i / K, k = i - n * K;
    size_t si = (size_t)k * N + n;
    if (*flag) dst[i] = f2bf(((const float*)src)[si]);
    else       dst[i] = ((const unsigned short*)src)[si];
}

// ---------------- xproj weight prep: column-permute + transpose + bf16 -----------
__global__ __launch_bounds__(256) void wt_xproj_kernel(
    const void* __restrict__ src, unsigned short* __restrict__ dst,
    const int* __restrict__ flag)
{
    int i = blockIdx.x * 256 + threadIdx.x;   // 288*512 = 147456
    if (i >= 147456) return;
    int c = i >> 9, k = i & 511;
    int s;
    if (c < 32) s = c;
    else if (c < 160) { int q = c - 32;  s = 32  + (q >> 3) + ((q & 7) << 4); }
    else             { int q = c - 160; s = 160 + (q >> 3) + ((q & 7) << 4); }
    size_t si = (size_t)k * 288 + s;
    if (*flag) dst[i] = f2bf(((const float*)src)[si]);
    else       dst[i] = ((const unsigned short*)src)[si];
}

// ---------------- bf16-MFMA GEMM, K=64/iter double panel (halved barriers) ---------
__global__ __launch_bounds__(256) void gemm_mfma_kernel(
    const void* __restrict__ Ain, int lda, long long sA,
    const unsigned short* __restrict__ Wt, int N, int K,
    const float* __restrict__ bias,
    void* __restrict__ Cout, int ldc, long long sC,
    int M, int act, int a_bf16, int c_bf16)
{
    __shared__ __align__(16) unsigned short As0[64][40], As1[64][40];   // [m][k] bf16
    __shared__ __align__(16) unsigned short Bs0[64][40], Bs1[64][40];   // [n][k] bf16
    const int tid = threadIdx.x;
    const int wave = tid >> 6, lane = tid & 63;
    const int bm = blockIdx.x * 64, bn = blockIdx.y * 64;
    const int col = lane & 15, quad = lane >> 4;

    f32x4 acc[4] = {{0.f,0.f,0.f,0.f},{0.f,0.f,0.f,0.f},{0.f,0.f,0.f,0.f},{0.f,0.f,0.f,0.f}};

    const int ar = tid >> 2, ak = (tid & 3) << 3;
    const int wn = tid & 63, wk = (tid >> 6) << 3;
    const bool wok = (bn + wn) < N;
    const unsigned short* wrow = Wt + (size_t)(bn + wn) * K;
    const int gm = bm + ar;
    const unsigned short* abf = (const unsigned short*)Ain + (size_t)blockIdx.z * sA
                                + (size_t)gm * lda;
    const float* af32 = (const float*)Ain + (size_t)blockIdx.z * sA + (size_t)gm * lda;

    for (int kt = 0; kt < K; kt += 64) {
        bfx8 a0 = {0,0,0,0,0,0,0,0}, a1 = {0,0,0,0,0,0,0,0};
        if (gm < M) {
            if (a_bf16) {
                a0 = *(const bfx8*)(abf + kt + ak);
                a1 = *(const bfx8*)(abf + kt + 32 + ak);
            } else {
                const float* ap = af32 + kt + ak;
                float4 v0 = *(const float4*)ap;
                float4 v1 = *(const float4*)(ap + 4);
                float4 v2 = *(const float4*)(ap + 32);
                float4 v3 = *(const float4*)(ap + 36);
                a0[0]=(short)f2bf(v0.x); a0[1]=(short)f2bf(v0.y);
                a0[2]=(short)f2bf(v0.z); a0[3]=(short)f2bf(v0.w);
                a0[4]=(short)f2bf(v1.x); a0[5]=(short)f2bf(v1.y);
                a0[6]=(short)f2bf(v1.z); a0[7]=(short)f2bf(v1.w);
                a1[0]=(short)f2bf(v2.x); a1[1]=(short)f2bf(v2.y);
                a1[2]=(short)f2bf(v2.z); a1[3]=(short)f2bf(v2.w);
                a1[4]=(short)f2bf(v3.x); a1[5]=(short)f2bf(v3.y);
                a1[6]=(short)f2bf(v3.z); a1[7]=(short)f2bf(v3.w);
            }
        }
        bfx8 b0 = {0,0,0,0,0,0,0,0}, b1 = {0,0,0,0,0,0,0,0};
        if (wok) {
            b0 = *(const bfx8*)(wrow + kt + wk);
            b1 = *(const bfx8*)(wrow + kt + 32 + wk);
        }
        __syncthreads();
        *(bfx8*)&As0[ar][ak] = a0;
        *(bfx8*)&As1[ar][ak] = a1;
        *(bfx8*)&Bs0[wn][wk] = b0;
        *(bfx8*)&Bs1[wn][wk] = b1;
        __syncthreads();
        bfx8 af0 = *(const bfx8*)&As0[wave * 16 + col][quad << 3];
        bfx8 af1 = *(const bfx8*)&As1[wave * 16 + col][quad << 3];
#pragma unroll
        for (int ct = 0; ct < 4; ++ct) {
            bfx8 bf0 = *(const bfx8*)&Bs0[ct * 16 + col][quad << 3];
            acc[ct] = __builtin_amdgcn_mfma_f32_16x16x32_bf16(af0, bf0, acc[ct], 0, 0, 0);
            bfx8 bf1 = *(const bfx8*)&Bs1[ct * 16 + col][quad << 3];
            acc[ct] = __builtin_amdgcn_mfma_f32_16x16x32_bf16(af1, bf1, acc[ct], 0, 0, 0);
        }
    }
#pragma unroll
    for (int ct = 0; ct < 4; ++ct) {
        int gn = bn + ct * 16 + col;
        if (gn >= N) continue;
        float bv = bias ? bias[gn] : 0.f;
#pragma unroll
        for (int r = 0; r < 4; ++r) {
            int gmo = bm + wave * 16 + quad * 4 + r;
            if (gmo < M) {
                float v = acc[ct][r] + bv;
                if (act == 1) v = fmaxf(v, 0.f);
                size_t co = (size_t)blockIdx.z * sC + (size_t)gmo * ldc + gn;
                if (c_bf16) ((unsigned short*)Cout)[co] = f2bf(v);
                else        ((float*)Cout)[co] = v;
            }
        }
    }
}

// ---------------- causal depthwise conv (K=4) + silu; optional fused z-silu --------
__global__ __launch_bounds__(256) void conv_silu_kernel(
    const float* __restrict__ xzbase, int ld, long long bstride,
    const float* __restrict__ conv_w, const float* __restrict__ conv_b,
    float* __restrict__ xs, int T, int rev_mode, float* __restrict__ zio)
{
    int idx = blockIdx.x * 256 + threadIdx.x;
    if (idx >= 2 * T * DI) return;
    int half = idx / (T * DI);
    int rem = idx - half * T * DI;
    int t = rem >> 9, d = rem & 511;
    const float* xzp = xzbase + (rev_mode ? 0 : (size_t)half * bstride);
    int rev = rev_mode ? half : 0;
    float acc = conv_b[d];
#pragma unroll
    for (int k = 0; k < 4; ++k) {
        int tt = t - 3 + k;
        if (tt >= 0) {
            int g = rev ? (T - 1 - tt) : tt;
            acc += conv_w[d * 4 + k] * xzp[(size_t)g * ld + d];
        }
    }
    xs[idx] = acc * sigm(acc);
    // fused in-place silu on z columns (one thread per (t,d): half==0 only)
    if (zio && half == 0) {
        float* p = zio + (size_t)t * 1024 + 512 + d;
        float z = *p;
        *p = z * sigm(z);
    }
}

// ---------------- dt projection (K=32) + softplus ----------------
__global__ __launch_bounds__(256) void dt_kernel(
    const float* __restrict__ xdbl, const float* __restrict__ dt_w,
    const float* __restrict__ dt_b, float* __restrict__ dtout, int T)
{
    int idx = blockIdx.x * 256 + threadIdx.x;
    if (idx >= 2 * T * DI) return;
    int half = idx / (T * DI);
    int rem = idx - half * T * DI;
    int t = rem >> 9, j = rem & 511;
    const float* a = xdbl + (size_t)half * T * XPN + (size_t)t * XPN;
    float acc = dt_b[j];
#pragma unroll
    for (int k = 0; k < 32; ++k) acc += a[k] * dt_w[k * DI + j];
    dtout[idx] = (acc > 20.f) ? acc : log1pf(__expf(acc));
}

#define TT 16
#define RS1 196      // part1 LDS row stride (dwords): 16 lanes x 12 + pad
#define RS2 392      // emit LDS row stride: B seg at 0, C seg at +196

// ---------------- chunked scan pass 1 (LDS-staged, bank-spread layout) -------------
__global__ __launch_bounds__(256) void scan_part1_kernel(
    const float* __restrict__ dt, const float* __restrict__ xdbl,
    const float* __restrict__ xs, const float* __restrict__ A_log,
    float* __restrict__ Sarr, float* __restrict__ H, int T, int NC, int LC)
{
    __shared__ __align__(16) float xb[TT][RS1];
    __shared__ float sdt[TT][16], sxs[TT][16];
    int b2 = blockIdx.x;
    int c = b2 % NC;
    int dpq = b2 / NC;
    int tid = threadIdx.x;
    int w = tid >> 6, lane = tid & 63;
    int sub = lane >> 4, l = lane & 15;
    int jb = w * 4 + sub;                 // block-local d index 0..15
    int hd = dpq * 16 + jb;
    int d = hd & 511;
    int half = (dpq * 16) >> 9;
    int d0 = (dpq * 16) & 511;
    f32x2 a2[4];
#pragma unroll
    for (int q = 0; q < 4; ++q) {
        a2[q][0] = -__expf(A_log[d * NS + 32 * q + l])      * L2E;   // n = l + 16*(2q)
        a2[q][1] = -__expf(A_log[d * NS + 32 * q + 16 + l]) * L2E;   // n = l + 16*(2q+1)
    }
    int t0 = c * LC, t1 = min(T, t0 + LC);
    const size_t dbase = (size_t)half * T * DI + d0;
    const float* rowb = xdbl + (size_t)half * T * XPN + 32;
    float S = 0.f;
    f32x2 h2[4] = {{0.f,0.f},{0.f,0.f},{0.f,0.f},{0.f,0.f}};
    int st = tid >> 4, sj = tid & 15;     // staging coords for dt/xs
    const int lo = 12 * l;
    for (int tt = t0; tt < t1; tt += TT) {
        __syncthreads();
        // stage B rows: 16t x 32 float4; dst chunked 12-dword per lane.
        // Over-reads past t1 (cross tail) stay inside d_ws and are never consumed.
#pragma unroll
        for (int q = 0; q < 2; ++q) {
            int fi = q * 256 + tid;
            int t = fi >> 5, g = fi & 31;
            float4 v = *(const float4*)(rowb + (size_t)(tt + t) * XPN + g * 4);
            *(float4*)&xb[t][12 * (g >> 1) + 4 * (g & 1)] = v;
        }
        {   // stage dt/xs scalars: 16t x 16d
            size_t g = dbase + (size_t)(tt + st) * DI + sj;
            sdt[st][sj] = dt[g];
            sxs[st][sj] = xs[g];
        }
        __syncthreads();
        int nt = min(TT, t1 - tt);
        int k = 0;
        for (; k + 2 <= nt; k += 2) {
            float dva = sdt[k][jb],     xva = sxs[k][jb];
            float dvb = sdt[k + 1][jb], xvb = sxs[k + 1][jb];
            float4 v0 = *(const float4*)&xb[k][lo];
            float4 v1 = *(const float4*)&xb[k][lo + 4];
            float4 w0 = *(const float4*)&xb[k + 1][lo];
            float4 w1 = *(const float4*)&xb[k + 1][lo + 4];
            f32x2 Ba[4] = {{v0.x,v0.y},{v0.z,v0.w},{v1.x,v1.y},{v1.z,v1.w}};
            f32x2 Bb[4] = {{w0.x,w0.y},{w0.z,w0.w},{w1.x,w1.y},{w1.z,w1.w}};
            float ua = dva * xva, ub = dvb * xvb;
            S += dva + dvb;
            f32x2 ua2 = {ua, ua}, ub2 = {ub, ub};
            f32x2 dva2 = {dva, dva}, dvb2 = {dvb, dvb};
#pragma unroll
            for (int q = 0; q < 4; ++q) {
                f32x2 ga = dva2 * a2[q];
                f32x2 ea; ea[0] = fexp2(ga[0]); ea[1] = fexp2(ga[1]);
                h2[q] = h2[q] * ea + ua2 * Ba[q];
                f32x2 gb = dvb2 * a2[q];
                f32x2 eb; eb[0] = fexp2(gb[0]); eb[1] = fexp2(gb[1]);
                h2[q] = h2[q] * eb + ub2 * Bb[q];
            }
        }
        if (k < nt) {
            float dv = sdt[k][jb], xv = sxs[k][jb];
            float4 v0 = *(const float4*)&xb[k][lo];
            float4 v1 = *(const float4*)&xb[k][lo + 4];
            f32x2 Bv[4] = {{v0.x,v0.y},{v0.z,v0.w},{v1.x,v1.y},{v1.z,v1.w}};
            float u = dv * xv;
            S += dv;
            f32x2 u2 = {u, u}, dv2 = {dv, dv};
#pragma unroll
            for (int q = 0; q < 4; ++q) {
                f32x2 g = dv2 * a2[q];
                f32x2 e; e[0] = fexp2(g[0]); e[1] = fexp2(g[1]);
                h2[q] = h2[q] * e + u2 * Bv[q];
            }
        }
    }
    size_t base = ((size_t)hd * NC + c) * 128 + l;
#pragma unroll
    for (int q = 0; q < 4; ++q) {
        H[base + 32 * q]      = h2[q][0];
        H[base + 32 * q + 16] = h2[q][1];
    }
    if (l == 0) Sarr[(size_t)hd * NC + c] = S;
}

// ---------------- chunked scan pass 2: serial combine (in-place H -> h_start) ------
__global__ __launch_bounds__(128) void scan_combine_kernel(
    const float* __restrict__ Sarr, float* __restrict__ H,
    const float* __restrict__ A_log, float* __restrict__ Hfinal, int NC)
{
    int hd = blockIdx.x;
    int d = hd & 511;
    int n = threadIdx.x;
    float a = -__expf(A_log[d * NS + n]) * L2E;
    size_t base = (size_t)hd * NC * 128 + n;
    float h = 0.f;
    for (int c = 0; c < NC; ++c) {
        size_t off = base + (size_t)c * 128;
        float p = fexp2(a * Sarr[(size_t)hd * NC + c]);
        float hh = H[off];
        H[off] = h;                // h_start for chunk c (exclusive prefix)
        h = p * h + hh;
    }
    if (Hfinal) Hfinal[(size_t)hd * 128 + n] = h;
}

// ---------------- chunked scan pass 3: LDS-staged replay + emit gated y (bf16) ------
__global__ __launch_bounds__(256) void scan_emit_kernel(
    const float* __restrict__ dt, const float* __restrict__ xdbl,
    const float* __restrict__ xs, const float* __restrict__ xz,
    const float* __restrict__ A_log, const float* __restrict__ Hstart,
    const float* __restrict__ Dp,
    unsigned short* __restrict__ y, int T, int NC, int LC)
{
    __shared__ __align__(16) float xb[TT][RS2];   // B seg at 0, C seg at +196
    __shared__ float sdt[TT][16], sxs[TT][16], sz[TT][16];
    int b2 = blockIdx.x;
    int c = b2 % NC;
    int dpq = b2 / NC;
    int tid = threadIdx.x;
    int w = tid >> 6, lane = tid & 63;
    int sub = lane >> 4, l = lane & 15;
    int jb = w * 4 + sub;
    int hd = dpq * 16 + jb;
    int d = hd & 511;
    int half = (dpq * 16) >> 9;
    int d0 = (dpq * 16) & 511;
    f32x2 a2[4];
#pragma unroll
    for (int q = 0; q < 4; ++q) {
        a2[q][0] = -__expf(A_log[d * NS + 32 * q + l])      * L2E;
        a2[q][1] = -__expf(A_log[d * NS + 32 * q + 16 + l]) * L2E;
    }
    const float Dv = Dp[d];
    size_t base = ((size_t)hd * NC + c) * 128 + l;
    f32x2 h2[4];
#pragma unroll
    for (int q = 0; q < 4; ++q) {
        h2[q][0] = Hstart[base + 32 * q];
        h2[q][1] = Hstart[base + 32 * q + 16];
    }
    int t0 = c * LC, t1 = min(T, t0 + LC);
    const size_t dbase = (size_t)half * T * DI + d0;
    const float* rowb = xdbl + (size_t)half * T * XPN + 32;
    int st = tid >> 4, sj = tid & 15;
    size_t ybase = (size_t)half * T * DI + d;
    const int lo = 12 * l;
    for (int tt = t0; tt < t1; tt += TT) {
        __syncthreads();
        // stage B+C rows: 16t x 64 float4; per-seg chunked 12-dword per lane.
#pragma unroll
        for (int q = 0; q < 4; ++q) {
            int fi = q * 256 + tid;
            int t = fi >> 6, g = fi & 63;
            int seg = g >> 5, gl = g & 31;
            float4 v = *(const float4*)(rowb + (size_t)(tt + t) * XPN + g * 4);
            *(float4*)&xb[t][seg * 196 + 12 * (gl >> 1) + 4 * (gl & 1)] = v;
        }
        {   // stage dt/xs/silu(z) scalars
            size_t g = dbase + (size_t)(tt + st) * DI + sj;
            sdt[st][sj] = dt[g];
            sxs[st][sj] = xs[g];
            int tg = half ? (T - 1 - (tt + st)) : (tt + st);
            sz[st][sj] = xz[(size_t)tg * 1024 + 512 + d0 + sj];
        }
        __syncthreads();
        int nt = min(TT, t1 - tt);
        for (int k = 0; k + 2 <= nt; k += 2) {
            float dva = sdt[k][jb],     xva = sxs[k][jb];
            float dvb = sdt[k + 1][jb], xvb = sxs[k + 1][jb];
            float ga = sz[k][jb], gb = sz[k + 1][jb];
            float4 v0 = *(const float4*)&xb[k][lo];
            float4 v1 = *(const float4*)&xb[k][lo + 4];
            float4 c0 = *(const float4*)&xb[k][196 + lo];
            float4 c1 = *(const float4*)&xb[k][196 + lo + 4];
            float4 w0 = *(const float4*)&xb[k + 1][lo];
            float4 w1 = *(const float4*)&xb[k + 1][lo + 4];
            float4 e0 = *(const float4*)&xb[k + 1][196 + lo];
            float4 e1 = *(const float4*)&xb[k + 1][196 + lo + 4];
            f32x2 Ba[4] = {{v0.x,v0.y},{v0.z,v0.w},{v1.x,v1.y},{v1.z,v1.w}};
            f32x2 Ca[4] = {{c0.x,c0.y},{c0.z,c0.w},{c1.x,c1.y},{c1.z,c1.w}};
            f32x2 Bb[4] = {{w0.x,w0.y},{w0.z,w0.w},{w1.x,w1.y},{w1.z,w1.w}};
            f32x2 Cb[4] = {{e0.x,e0.y},{e0.z,e0.w},{e1.x,e1.y},{e1.z,e1.w}};
            float ua = dva * xva, ub = dvb * xvb;
            f32x2 ua2 = {ua, ua}, ub2 = {ub, ub};
            f32x2 dva2 = {dva, dva}, dvb2 = {dvb, dvb};
            f32x2 pa2 = {0.f, 0.f}, pb2 = {0.f, 0.f};
#pragma unroll
            for (int q = 0; q < 4; ++q) {
                f32x2 gaa = dva2 * a2[q];
                f32x2 ea; ea[0] = fexp2(gaa[0]); ea[1] = fexp2(gaa[1]);
                h2[q] = h2[q] * ea + ua2 * Ba[q];
                pa2 += h2[q] * Ca[q];
            }
#pragma unroll
            for (int q = 0; q < 4; ++q) {
                f32x2 gbb = dvb2 * a2[q];
                f32x2 eb; eb[0] = fexp2(gbb[0]); eb[1] = fexp2(gbb[1]);
                h2[q] = h2[q] * eb + ub2 * Bb[q];
                pb2 += h2[q] * Cb[q];
            }
            float pa = pa2[0] + pa2[1], pb = pb2[0] + pb2[1];
            pa += __shfl_xor(pa, 1, 64);  pb += __shfl_xor(pb, 1, 64);
            pa += __shfl_xor(pa, 2, 64);  pb += __shfl_xor(pb, 2, 64);
            pa += __shfl_xor(pa, 4, 64);  pb += __shfl_xor(pb, 4, 64);
            pa += __shfl_xor(pa, 8, 64);  pb += __shfl_xor(pb, 8, 64);
            if (l == 0) {
                y[ybase + (size_t)(tt + k) * DI]     = f2bf((pa + xva * Dv) * ga);
                y[ybase + (size_t)(tt + k + 1) * DI] = f2bf((pb + xvb * Dv) * gb);
            }
        }
    }
}

// ---------------- cross: last-step readout (permuted C layout) ----------------
__global__ __launch_bounds__(64) void cross_readout_kernel(
    const float* __restrict__ Hfinal, const float* __restrict__ xdbl,
    const float* __restrict__ xs, const float* __restrict__ xz,
    const float* __restrict__ Dp, float* __restrict__ ylast, int T)
{
    int hd = blockIdx.x;
    int half = hd >> 9, d = hd & 511;
    int lane = threadIdx.x;
    xdbl += (size_t)half * T * XPN;
    xs   += (size_t)half * T * DI;
    xz   += (size_t)half * T * 1024;
    float h0 = Hfinal[(size_t)hd * 128 + lane];          // state n = lane
    float h1 = Hfinal[(size_t)hd * 128 + 64 + lane];     // state n = 64+lane
    const float* xl = xdbl + (size_t)(T - 1) * XPN;
    int pos = 160 + (lane & 15) * 8 + (lane >> 4);
    float C0 = xl[pos];            // n = lane
    float C1 = xl[pos + 4];        // n = 64+lane
    float p = h0 * C0 + h1 * C1;
#pragma unroll
    for (int off = 32; off > 0; off >>= 1) p += __shfl_down(p, off, 64);
    if (lane == 0) {
        float xlast = xs[(size_t)(T - 1) * DI + d];
        float zl = xz[(size_t)(T - 1) * 1024 + 512 + d];
        ylast[half * DI + d] = (p + xlast * Dp[d]) * (zl * sigm(zl));
    }
}

// ---------------- row softmax + scatter into both cross sequences (bf16 SEQ) -------
__global__ __launch_bounds__(256) void softmax_scatter_kernel(
    const float* __restrict__ yo, unsigned short* __restrict__ seq, int T)
{
    __shared__ float sm[4];
    const int t = blockIdx.x, half = blockIdx.y, tid = threadIdx.x;
    const float* row = yo + (size_t)half * T * DI + (size_t)t * DI;
    float v0 = row[tid], v1 = row[tid + 256];
    float m = fmaxf(v0, v1);
#pragma unroll
    for (int o = 32; o > 0; o >>= 1) m = fmaxf(m, __shfl_xor(m, o, 64));
    if ((tid & 63) == 0) sm[tid >> 6] = m;
    __syncthreads();
    m = fmaxf(fmaxf(sm[0], sm[1]), fmaxf(sm[2], sm[3]));
    __syncthreads();
    float e0 = __expf(v0 - m), e1 = __expf(v1 - m);
    float s = e0 + e1;
#pragma unroll
    for (int o = 32; o > 0; o >>= 1) s += __shfl_xor(s, o, 64);
    if ((tid & 63) == 0) sm[tid >> 6] = s;
    __syncthreads();
    s = sm[0] + sm[1] + sm[2] + sm[3];
    float inv = 1.f / s;
    unsigned short b0 = f2bf(e0 * inv), b1 = f2bf(e1 * inv);
    unsigned short* seq_fi = seq;
    unsigned short* seq_if = seq + (size_t)TC * 1024;
    if (half == 0) {
        unsigned short* d1 = seq_fi + (size_t)t * 1024;
        unsigned short* d2 = seq_if + (size_t)t * 1024 + 512;
        d1[tid] = b0; d1[tid + 256] = b1;
        d2[tid] = b0; d2[tid + 256] = b1;
    } else {
        int tg = T - 1 - t;
        unsigned short* d1 = seq_fi + (size_t)tg * 1024 + 512;
        unsigned short* d2 = seq_if + (size_t)tg * 1024;
        d1[tid] = b0; d1[tid + 256] = b1;
        d2[tid] = b0; d2[tid + 256] = b1;
    }
}

// ---------------- cls-token rows of the two sequences (bf16) ----------------
__global__ __launch_bounds__(256) void cls_rows_kernel(
    const float* __restrict__ cls1, const float* __restrict__ cls2,
    unsigned short* __restrict__ seq)
{
    int i = blockIdx.x * 256 + threadIdx.x;   // 0..2047
    if (i < 1024)
        seq[(size_t)(TC - 1) * 1024 + i] = f2bf(cls1[i]);
    else
        seq[(size_t)TC * 1024 + (size_t)(TC - 1) * 1024 + (i - 1024)] = f2bf(cls2[i - 1024]);
}

// ---------------- vec [512] @ out_w [512,512] -> [512] ----------------
__global__ __launch_bounds__(256) void vecmat_kernel(
    const float* __restrict__ ylast, const float* __restrict__ Wout,
    float* __restrict__ olast)
{
    int half = blockIdx.y;
    int j = blockIdx.x * 256 + threadIdx.x;
    const float* v = ylast + half * DI;
    float acc = 0.f;
    for (int k = 0; k < DI; ++k) acc += v[k] * Wout[k * DI + j];
    olast[half * DI + j] = acc;
}

// ---------------- final classifier -> f32 [2] ----------------
__global__ __launch_bounds__(256) void final_kernel(
    const float* __restrict__ ol, const float* __restrict__ cw,
    const float* __restrict__ cb, float* __restrict__ out)
{
    __shared__ float s0[4], s1[4];
    int tid = threadIdx.x;
    float a0 = 0.f, a1 = 0.f;
    for (int j = tid; j < 1024; j += 256) {
        float v = ol[j];
        a0 += v * cw[2 * j];
        a1 += v * cw[2 * j + 1];
    }
#pragma unroll
    for (int o = 32; o > 0; o >>= 1) { a0 += __shfl_xor(a0, o, 64); a1 += __shfl_xor(a1, o, 64); }
    if ((tid & 63) == 0) { s0[tid >> 6] = a0; s1[tid >> 6] = a1; }
    __syncthreads();
    if (tid == 0) {
        out[0] = s0[0] + s0[1] + s0[2] + s0[3] + cb[0];
        out[1] = s1[0] + s1[1] + s1[2] + s1[3] + cb[1];
    }
}

extern "C" void kernel_launch(void* const* d_in, const int* in_sizes, int n_in,
                              void* d_out, int out_size, void* d_ws, size_t ws_size,
                              hipStream_t stream)
{
    float* out = (float*)d_out;
    float* ws = (float*)d_ws;

    // ---- input-order resolution via in_sizes (dict vs signature order) ----
    static const int sig_map[25] = {0,1,2,3,4,23,24,5,6,7,8,9,10,11,12,13,
                                    14,15,16,17,18,19,20,21,22};
    int idx[25];
    bool dict_order = (n_in >= 7 && in_sizes[6] == 2);
    for (int i = 0; i < 25; ++i) idx[i] = dict_order ? i : sig_map[i];

    // ---- aliased workspace layout (f32 elements) ----
    const size_t A0 = 0;         // x(bf16) -> dt_simple -> yo -> XSC         (2,098,176)
    const size_t B0 = 2098176;   // f(bf16) / S_S -> XDC                      (1,180,224)
    const size_t C0 = 3278400;   // XZS / XZC (XZC spans ..7,474,752)         (2,097,152)
    const size_t D0 = 5375552;   // XS                                        (2,097,152)
    const size_t E0 = 7472704;   // XDBL                                      (1,179,648)
    const size_t F0 = 8652352;   // y(bf16) / YS                              (2,097,152)
    const size_t G0 = 10749504;  // H_S (NC=32, 4,194,304) -> SEQ(bf16)       (4,196,352)
    const size_t YL0 = 14945856; // 1024
    const size_t OL0 = 14946880; // 1024
    const size_t DT_S = A0;
    const size_t S_S  = B0 + 524288;     // after bf16 f (f = 1M ushorts = 524,288 fl)
    const size_t H_S  = G0;              // 1024*32*128 = 4,194,304
    const size_t DT_C = 7474752;
    const size_t H_C  = 9572928;         // 1024*33*128 = 4,325,376 -> ends 13,898,304
    const size_t S_C  = 13898304;        // 1024*33 = 33,792
    const size_t HFIN = 14029376;        // 131,072
    size_t o = 14947904;
    const size_t P_FEATW = o; o += 524288;   // bf16 Wt[512][1024]
    const size_t P_FEATB = o; o += 512;
    const size_t P_CLS1  = o; o += 1024;
    const size_t P_CLS2  = o; o += 1024;
    const size_t P_CLSW  = o; o += 2048;
    const size_t P_CLSB  = o; o += 4;
    const size_t P_MINW  = o; o += 524288;   // bf16 Wt[1024][512]
    const size_t P_MCW   = o; o += 2048;
    const size_t P_MCB   = o; o += 512;
    const size_t P_MXP   = o; o += 147456;   // bf16 Wt[288][512]
    const size_t P_MDTW  = o; o += 16384;
    const size_t P_MDTB  = o; o += 512;
    const size_t P_MAL   = o; o += 65536;
    const size_t P_MD    = o; o += 512;
    const size_t P_MOW   = o; o += 262144;   // bf16 Wt[512][512]
    const size_t P_CINW  = o; o += 1048576;  // bf16 Wt[1024][1024]
    const size_t P_CCW   = o; o += 2048;
    const size_t P_CCB   = o; o += 512;
    const size_t P_CXP   = o; o += 147456;   // bf16 Wt[288][512]
    const size_t P_CDTW  = o; o += 16384;
    const size_t P_CDTB  = o; o += 512;
    const size_t P_CAL   = o; o += 65536;
    const size_t P_CD    = o; o += 512;
    const size_t P_COW   = o; o += 262144;
    const size_t OFF_FLAG = o;               // 1 int

    int* flagp = (int*)(ws + OFF_FLAG);
    unsigned short* XB   = (unsigned short*)(ws + A0);
    unsigned short* FB   = (unsigned short*)(ws + B0);
    unsigned short* YB   = (unsigned short*)(ws + F0);
    unsigned short* SEQB = (unsigned short*)(ws + G0);
    unsigned short* WT_FEATW = (unsigned short*)(ws + P_FEATW);
    unsigned short* WT_MINW  = (unsigned short*)(ws + P_MINW);
    unsigned short* WT_MXP   = (unsigned short*)(ws + P_MXP);
    unsigned short* WT_MOW   = (unsigned short*)(ws + P_MOW);
    unsigned short* WT_CINW  = (unsigned short*)(ws + P_CINW);
    unsigned short* WT_CXP   = (unsigned short*)(ws + P_CXP);

    // 0) detect input dtype
    detect_kernel<<<1, 256, 0, stream>>>((const unsigned short*)d_in[idx[0]], flagp);

    // 1) widen non-GEMM inputs (18 plain) + x->bf16 + 6 GEMM weights (bf16, transposed)
    WDT tab;
    const int lg[18]  = {2,3,4,5,6,8,9,11,12,13,14,17,18,20,21,22,23,24};
    const int nsl[25] = {2097152, 524288, 512, 1024, 1024, 2048, 2,
                         524288, 2048, 512, 147456, 16384, 512, 65536, 512, 262144,
                         1048576, 2048, 512, 147456, 16384, 512, 65536, 512, 262144};
    float* dstl[25] = {
        nullptr, nullptr, ws + P_FEATB, ws + P_CLS1, ws + P_CLS2,
        ws + P_CLSW, ws + P_CLSB,
        nullptr, ws + P_MCW, ws + P_MCB, nullptr, ws + P_MDTW, ws + P_MDTB,
        ws + P_MAL, ws + P_MD, nullptr,
        nullptr, ws + P_CCW, ws + P_CCB, nullptr, ws + P_CDTW, ws + P_CDTB,
        ws + P_CAL, ws + P_CD, ws + P_COW};
    for (int i = 0; i < 18; ++i) {
        int s = lg[i];
        tab.e[i].src = d_in[idx[s]];
        tab.e[i].dst = dstl[s];
        tab.e[i].n = nsl[s];
    }
    widen_all_kernel<<<dim3(128, 18), 256, 0, stream>>>(tab, flagp);
    x2bf_kernel<<<8192, 256, 0, stream>>>(d_in[idx[0]], XB, 2097152, flagp);
    wt_plain_kernel<<<2048, 256, 0, stream>>>(d_in[idx[1]],  WT_FEATW, 1024, 512,  flagp);
    wt_plain_kernel<<<2048, 256, 0, stream>>>(d_in[idx[7]],  WT_MINW,  512,  1024, flagp);
    wt_plain_kernel<<<1024, 256, 0, stream>>>(d_in[idx[15]], WT_MOW,   512,  512,  flagp);
    wt_plain_kernel<<<4096, 256, 0, stream>>>(d_in[idx[16]], WT_CINW,  1024, 1024, flagp);
    wt_xproj_kernel<<<576, 256, 0, stream>>>(d_in[idx[10]], WT_MXP, flagp);
    wt_xproj_kernel<<<576, 256, 0, stream>>>(d_in[idx[19]], WT_CXP, flagp);

    // 2) f = relu(x @ feat_w + feat_b)        A(bf16) -> B(bf16)
    gemm_mfma_kernel<<<dim3(32, 8, 1), 256, 0, stream>>>(XB, 1024, 0, WT_FEATW, 512, 1024,
                                                         ws + P_FEATB, FB, 512, 0,
                                                         2048, 1, 1, 1);
    // 3) xz = f @ m_in_w                      B(bf16) -> C(f32)
    gemm_mfma_kernel<<<dim3(32, 16, 1), 256, 0, stream>>>(FB, 512, 0, WT_MINW, 1024, 512,
                                                          nullptr, ws + C0, 1024, 0,
                                                          2048, 0, 1, 0);
    // 4) conv+silu both dirs + fused in-place z-silu    C -> D (+C z-cols)
    conv_silu_kernel<<<8192, 256, 0, stream>>>(ws + C0, 1024, 0, ws + P_MCW, ws + P_MCB,
                                               ws + D0, 2048, 1, ws + C0);
    // 5) x_dbl = xs @ m_xproj_w (permuted)    D(f32) -> E(f32)
    gemm_mfma_kernel<<<dim3(32, 5, 2), 256, 0, stream>>>(ws + D0, 512, 2048LL * 512, WT_MXP,
                                                         288, 512, nullptr, ws + E0, 288,
                                                         2048LL * 288, 2048, 0, 0, 0);
    // 5b) dt = softplus(x_dbl[:, :32] @ dt_w + dt_b)   E -> DT_S (A)
    dt_kernel<<<8192, 256, 0, stream>>>(ws + E0, ws + P_MDTW, ws + P_MDTB, ws + DT_S, 2048);
    // 6) chunked scan: T=2048, 32 chunks x 64 (64 dpq x 32 c = 2048 blocks)
    scan_part1_kernel<<<2048, 256, 0, stream>>>(ws + DT_S, ws + E0, ws + D0, ws + P_MAL,
                                                ws + S_S, ws + H_S, 2048, 32, 64);
    scan_combine_kernel<<<1024, 128, 0, stream>>>(ws + S_S, ws + H_S, ws + P_MAL, nullptr, 32);
    // 6b) emit with fused gating, bf16 y out
    scan_emit_kernel<<<2048, 256, 0, stream>>>(ws + DT_S, ws + E0, ws + D0, ws + C0,
                                               ws + P_MAL, ws + H_S, ws + P_MD,
                                               YB, 2048, 32, 64);
    // 7) yo = y @ m_out_w                     F(bf16) -> A(f32 yo)
    gemm_mfma_kernel<<<dim3(32, 8, 2), 256, 0, stream>>>(YB, 512, 2048LL * 512, WT_MOW,
                                                         512, 512, nullptr, ws + A0, 512,
                                                         2048LL * 512, 2048, 0, 1, 0);
    // 8) cls-token rows into SEQ (bf16)       P -> G
    cls_rows_kernel<<<8, 256, 0, stream>>>(ws + P_CLS1, ws + P_CLS2, SEQB);
    // 9) softmax + scatter (bf16 SEQ)         A -> G
    softmax_scatter_kernel<<<dim3(2048, 2), 256, 0, stream>>>(ws + A0, SEQB, 2048);
    // 10) cross in-proj                       G(bf16) -> C(f32 XZC)
    gemm_mfma_kernel<<<dim3(33, 16, 2), 256, 0, stream>>>(SEQB, 1024, 2049LL * 1024, WT_CINW,
                                                          1024, 1024, nullptr, ws + C0, 1024,
                                                          2049LL * 1024, 2049, 0, 1, 0);
    // 11) cross conv+silu (no fused z)        C -> A (XSC)
    conv_silu_kernel<<<8196, 256, 0, stream>>>(ws + C0, 1024, 2049LL * 1024, ws + P_CCW,
                                               ws + P_CCB, ws + A0, 2049, 0, nullptr);
    // 12) cross x_dbl (permuted)              A(f32) -> B(f32 XDC)
    gemm_mfma_kernel<<<dim3(33, 5, 2), 256, 0, stream>>>(ws + A0, 512, 2049LL * 512, WT_CXP,
                                                         288, 512, nullptr, ws + B0, 288,
                                                         2049LL * 288, 2049, 0, 0, 0);
    // 12b) cross dt                           B -> DT_C
    dt_kernel<<<8196, 256, 0, stream>>>(ws + B0, ws + P_CDTW, ws + P_CDTB, ws + DT_C, 2049);
    // 13) cross chunked scan: T=2049, 33 chunks x 64 (64 dpq x 33 c = 2112 blocks)
    scan_part1_kernel<<<2112, 256, 0, stream>>>(ws + DT_C, ws + B0, ws + A0, ws + P_CAL,
                                                ws + S_C, ws + H_C, 2049, 33, 64);
    scan_combine_kernel<<<1024, 128, 0, stream>>>(ws + S_C, ws + H_C, ws + P_CAL, ws + HFIN, 33);
    cross_readout_kernel<<<1024, 64, 0, stream>>>(ws + HFIN, ws + B0, ws + A0, ws + C0,
                                                  ws + P_CD, ws + YL0, 2049);
    // 14) out-projection of last rows         YL -> OL
    vecmat_kernel<<<dim3(2, 2), 256, 0, stream>>>(ws + YL0, ws + P_COW, ws + OL0);
    // 15) classifier                          OL -> out (f32)
    final_kernel<<<1, 256, 0, stream>>>(ws + OL0, ws + P_CLSW, ws + P_CLSB, out);
}

// Round 15
// 496.217 us; speedup vs baseline: 1.0313x; 1.0198x over previous
//
#include <hip/hip_runtime.h>
#include <hip/hip_bf16.h>

#define TC    2049
#define DI    512
#define NS    128
#define XPN   288   // DT_RANK + 2*N_STATE = 32 + 256

typedef short bfx8 __attribute__((ext_vector_type(8)));
typedef float f32x4 __attribute__((ext_vector_type(4)));
typedef float f32x2 __attribute__((ext_vector_type(2)));

__device__ __forceinline__ float us2f(unsigned short u) {
    union { unsigned int i; float f; } v; v.i = ((unsigned int)u) << 16; return v.f;
}
__device__ __forceinline__ unsigned short f2bf(float f) {
    unsigned int u = __float_as_uint(f);
    u = (u + 0x7FFF + ((u >> 16) & 1)) >> 16;   // round-to-nearest-even
    return (unsigned short)u;
}
__device__ __forceinline__ float sigm(float x) { return 1.f / (1.f + __expf(-x)); }

#define L2E 1.4426950408889634f

// raw v_exp_f32 (args are always <= 0 here; native flush behavior is correct)
__device__ __forceinline__ float fexp2(float x) {
#if __has_builtin(__builtin_amdgcn_exp2f)
    return __builtin_amdgcn_exp2f(x);
#else
    return __expf(x * 0.6931471805599453f);
#endif
}

// ---------------- dtype sniffing: bf16 inputs (flag=0) vs f32 inputs (flag=1) -----
__global__ void detect_kernel(const unsigned short* __restrict__ x, int* __restrict__ flag) {
    __shared__ int cnt;
    int tid = threadIdx.x;
    if (tid == 0) cnt = 0;
    __syncthreads();
    unsigned short u = x[tid];
    int e = (u >> 7) & 0xFF;
    int insane = (u != 0 && (e < 97 || e > 157)) ? 1 : 0;
    atomicAdd(&cnt, insane);
    __syncthreads();
    if (tid == 0) *flag = (cnt >= 64) ? 1 : 0;
}

// ---------------- widen inputs to f32 in workspace (18 plain entries) ----------------
struct WD { const void* src; float* dst; int n; };
struct WDT { WD e[18]; };
__global__ __launch_bounds__(256) void widen_all_kernel(WDT tab, const int* __restrict__ flag) {
    WD d = tab.e[blockIdx.y];
    const int f = *flag;
    const int stride = gridDim.x * 256;
    int i = blockIdx.x * 256 + threadIdx.x;
    if (f) {
        const float* s = (const float*)d.src;
        for (; i < d.n; i += stride) d.dst[i] = s[i];
    } else {
        const unsigned short* s = (const unsigned short*)d.src;
        for (; i < d.n; i += stride) d.dst[i] = us2f(s[i]);
    }
}

// ---------------- x -> bf16 (identity copy for bf16 inputs) ----------------
__global__ __launch_bounds__(256) void x2bf_kernel(
    const void* __restrict__ src, unsigned short* __restrict__ dst, int n,
    const int* __restrict__ flag)
{
    int i = blockIdx.x * 256 + threadIdx.x;
    if (i >= n) return;
    dst[i] = (*flag) ? f2bf(((const float*)src)[i]) : ((const unsigned short*)src)[i];
}

// ---------------- GEMM weight prep: LDS-tiled transpose + bf16, Wt[n][k] ----------
// 32x32 tiles: coalesced reads along n, coalesced writes along k. K,N % 32 == 0.
__global__ __launch_bounds__(256) void wt_plain_kernel(
    const void* __restrict__ src, unsigned short* __restrict__ dst,
    int K, int N, const int* __restrict__ flag)
{
    __shared__ unsigned int tile[32][33];
    int tk0 = blockIdx.x * 32;   // k tile origin
    int tn0 = blockIdx.y * 32;   // n tile origin
    int tx = threadIdx.x & 31, ty = threadIdx.x >> 5;   // 32 x 8
    const int f = *flag;
#pragma unroll
    for (int r = 0; r < 4; ++r) {
        int k = tk0 + ty + 8 * r;
        unsigned int raw;
        if (f) raw = ((const unsigned int*)src)[(size_t)k * N + tn0 + tx];
        else   raw = ((const unsigned short*)src)[(size_t)k * N + tn0 + tx];
        tile[ty + 8 * r][tx] = raw;
    }
    __syncthreads();
#pragma unroll
    for (int r = 0; r < 4; ++r) {
        int n = tn0 + ty + 8 * r;
        unsigned int raw = tile[tx][ty + 8 * r];
        unsigned short v = f ? f2bf(__uint_as_float(raw)) : (unsigned short)raw;
        dst[(size_t)n * K + tk0 + tx] = v;
    }
}

// ---------------- xproj weight prep: column-permute + transpose + bf16 -----------
__global__ __launch_bounds__(256) void wt_xproj_kernel(
    const void* __restrict__ src, unsigned short* __restrict__ dst,
    const int* __restrict__ flag)
{
    int i = blockIdx.x * 256 + threadIdx.x;   // 288*512 = 147456
    if (i >= 147456) return;
    int c = i >> 9, k = i & 511;
    int s;
    if (c < 32) s = c;
    else if (c < 160) { int q = c - 32;  s = 32  + (q >> 3) + ((q & 7) << 4); }
    else             { int q = c - 160; s = 160 + (q >> 3) + ((q & 7) << 4); }
    size_t si = (size_t)k * 288 + s;
    if (*flag) dst[i] = f2bf(((const float*)src)[si]);
    else       dst[i] = ((const unsigned short*)src)[si];
}

// ---------------- bf16-MFMA GEMM, K=64/iter double panel (halved barriers) ---------
__global__ __launch_bounds__(256) void gemm_mfma_kernel(
    const void* __restrict__ Ain, int lda, long long sA,
    const unsigned short* __restrict__ Wt, int N, int K,
    const float* __restrict__ bias,
    void* __restrict__ Cout, int ldc, long long sC,
    int M, int act, int a_bf16, int c_bf16)
{
    __shared__ __align__(16) unsigned short As0[64][40], As1[64][40];   // [m][k] bf16
    __shared__ __align__(16) unsigned short Bs0[64][40], Bs1[64][40];   // [n][k] bf16
    const int tid = threadIdx.x;
    const int wave = tid >> 6, lane = tid & 63;
    const int bm = blockIdx.x * 64, bn = blockIdx.y * 64;
    const int col = lane & 15, quad = lane >> 4;

    f32x4 acc[4] = {{0.f,0.f,0.f,0.f},{0.f,0.f,0.f,0.f},{0.f,0.f,0.f,0.f},{0.f,0.f,0.f,0.f}};

    const int ar = tid >> 2, ak = (tid & 3) << 3;
    const int wn = tid & 63, wk = (tid >> 6) << 3;
    const bool wok = (bn + wn) < N;
    const unsigned short* wrow = Wt + (size_t)(bn + wn) * K;
    const int gm = bm + ar;
    const unsigned short* abf = (const unsigned short*)Ain + (size_t)blockIdx.z * sA
                                + (size_t)gm * lda;
    const float* af32 = (const float*)Ain + (size_t)blockIdx.z * sA + (size_t)gm * lda;

    for (int kt = 0; kt < K; kt += 64) {
        bfx8 a0 = {0,0,0,0,0,0,0,0}, a1 = {0,0,0,0,0,0,0,0};
        if (gm < M) {
            if (a_bf16) {
                a0 = *(const bfx8*)(abf + kt + ak);
                a1 = *(const bfx8*)(abf + kt + 32 + ak);
            } else {
                const float* ap = af32 + kt + ak;
                float4 v0 = *(const float4*)ap;
                float4 v1 = *(const float4*)(ap + 4);
                float4 v2 = *(const float4*)(ap + 32);
                float4 v3 = *(const float4*)(ap + 36);
                a0[0]=(short)f2bf(v0.x); a0[1]=(short)f2bf(v0.y);
                a0[2]=(short)f2bf(v0.z); a0[3]=(short)f2bf(v0.w);
                a0[4]=(short)f2bf(v1.x); a0[5]=(short)f2bf(v1.y);
                a0[6]=(short)f2bf(v1.z); a0[7]=(short)f2bf(v1.w);
                a1[0]=(short)f2bf(v2.x); a1[1]=(short)f2bf(v2.y);
                a1[2]=(short)f2bf(v2.z); a1[3]=(short)f2bf(v2.w);
                a1[4]=(short)f2bf(v3.x); a1[5]=(short)f2bf(v3.y);
                a1[6]=(short)f2bf(v3.z); a1[7]=(short)f2bf(v3.w);
            }
        }
        bfx8 b0 = {0,0,0,0,0,0,0,0}, b1 = {0,0,0,0,0,0,0,0};
        if (wok) {
            b0 = *(const bfx8*)(wrow + kt + wk);
            b1 = *(const bfx8*)(wrow + kt + 32 + wk);
        }
        __syncthreads();
        *(bfx8*)&As0[ar][ak] = a0;
        *(bfx8*)&As1[ar][ak] = a1;
        *(bfx8*)&Bs0[wn][wk] = b0;
        *(bfx8*)&Bs1[wn][wk] = b1;
        __syncthreads();
        bfx8 af0 = *(const bfx8*)&As0[wave * 16 + col][quad << 3];
        bfx8 af1 = *(const bfx8*)&As1[wave * 16 + col][quad << 3];
#pragma unroll
        for (int ct = 0; ct < 4; ++ct) {
            bfx8 bf0 = *(const bfx8*)&Bs0[ct * 16 + col][quad << 3];
            acc[ct] = __builtin_amdgcn_mfma_f32_16x16x32_bf16(af0, bf0, acc[ct], 0, 0, 0);
            bfx8 bf1 = *(const bfx8*)&Bs1[ct * 16 + col][quad << 3];
            acc[ct] = __builtin_amdgcn_mfma_f32_16x16x32_bf16(af1, bf1, acc[ct], 0, 0, 0);
        }
    }
#pragma unroll
    for (int ct = 0; ct < 4; ++ct) {
        int gn = bn + ct * 16 + col;
        if (gn >= N) continue;
        float bv = bias ? bias[gn] : 0.f;
#pragma unroll
        for (int r = 0; r < 4; ++r) {
            int gmo = bm + wave * 16 + quad * 4 + r;
            if (gmo < M) {
                float v = acc[ct][r] + bv;
                if (act == 1) v = fmaxf(v, 0.f);
                size_t co = (size_t)blockIdx.z * sC + (size_t)gmo * ldc + gn;
                if (c_bf16) ((unsigned short*)Cout)[co] = f2bf(v);
                else        ((float*)Cout)[co] = v;
            }
        }
    }
}

// ---------------- causal depthwise conv (K=4) + silu; optional fused z-silu --------
__global__ __launch_bounds__(256) void conv_silu_kernel(
    const float* __restrict__ xzbase, int ld, long long bstride,
    const float* __restrict__ conv_w, const float* __restrict__ conv_b,
    float* __restrict__ xs, int T, int rev_mode, float* __restrict__ zio)
{
    int idx = blockIdx.x * 256 + threadIdx.x;
    if (idx >= 2 * T * DI) return;
    int half = idx / (T * DI);
    int rem = idx - half * T * DI;
    int t = rem >> 9, d = rem & 511;
    const float* xzp = xzbase + (rev_mode ? 0 : (size_t)half * bstride);
    int rev = rev_mode ? half : 0;
    float acc = conv_b[d];
#pragma unroll
    for (int k = 0; k < 4; ++k) {
        int tt = t - 3 + k;
        if (tt >= 0) {
            int g = rev ? (T - 1 - tt) : tt;
            acc += conv_w[d * 4 + k] * xzp[(size_t)g * ld + d];
        }
    }
    xs[idx] = acc * sigm(acc);
    // fused in-place silu on z columns (one thread per (t,d): half==0 only)
    if (zio && half == 0) {
        float* p = zio + (size_t)t * 1024 + 512 + d;
        float z = *p;
        *p = z * sigm(z);
    }
}

// ---------------- dt projection (K=32) + softplus ----------------
__global__ __launch_bounds__(256) void dt_kernel(
    const float* __restrict__ xdbl, const float* __restrict__ dt_w,
    const float* __restrict__ dt_b, float* __restrict__ dtout, int T)
{
    int idx = blockIdx.x * 256 + threadIdx.x;
    if (idx >= 2 * T * DI) return;
    int half = idx / (T * DI);
    int rem = idx - half * T * DI;
    int t = rem >> 9, j = rem & 511;
    const float* a = xdbl + (size_t)half * T * XPN + (size_t)t * XPN;
    float acc = dt_b[j];
#pragma unroll
    for (int k = 0; k < 32; ++k) acc += a[k] * dt_w[k * DI + j];
    dtout[idx] = (acc > 20.f) ? acc : log1pf(__expf(acc));
}

#define TT 16
#define RS1 196      // part1 LDS row stride (dwords): 16 lanes x 12 + pad
#define RS2 392      // emit LDS row stride: B seg at 0, C seg at +196

// ---------------- chunked scan pass 1 (LDS-staged, bank-spread layout) -------------
__global__ __launch_bounds__(256) void scan_part1_kernel(
    const float* __restrict__ dt, const float* __restrict__ xdbl,
    const float* __restrict__ xs, const float* __restrict__ A_log,
    float* __restrict__ Sarr, float* __restrict__ H, int T, int NC, int LC)
{
    __shared__ __align__(16) float xb[TT][RS1];
    __shared__ float sdt[TT][16], sxs[TT][16];
    int b2 = blockIdx.x;
    int c = b2 % NC;
    int dpq = b2 / NC;
    int tid = threadIdx.x;
    int w = tid >> 6, lane = tid & 63;
    int sub = lane >> 4, l = lane & 15;
    int jb = w * 4 + sub;                 // block-local d index 0..15
    int hd = dpq * 16 + jb;
    int d = hd & 511;
    int half = (dpq * 16) >> 9;
    int d0 = (dpq * 16) & 511;
    f32x2 a2[4];
#pragma unroll
    for (int q = 0; q < 4; ++q) {
        a2[q][0] = -__expf(A_log[d * NS + 32 * q + l])      * L2E;   // n = l + 16*(2q)
        a2[q][1] = -__expf(A_log[d * NS + 32 * q + 16 + l]) * L2E;   // n = l + 16*(2q+1)
    }
    int t0 = c * LC, t1 = min(T, t0 + LC);
    const size_t dbase = (size_t)half * T * DI + d0;
    const float* rowb = xdbl + (size_t)half * T * XPN + 32;
    float S = 0.f;
    f32x2 h2[4] = {{0.f,0.f},{0.f,0.f},{0.f,0.f},{0.f,0.f}};
    int st = tid >> 4, sj = tid & 15;     // staging coords for dt/xs
    const int lo = 12 * l;
    for (int tt = t0; tt < t1; tt += TT) {
        __syncthreads();
        // stage B rows: 16t x 32 float4; dst chunked 12-dword per lane.
        // Over-reads past t1 (cross tail) stay inside d_ws and are never consumed.
#pragma unroll
        for (int q = 0; q < 2; ++q) {
            int fi = q * 256 + tid;
            int t = fi >> 5, g = fi & 31;
            float4 v = *(const float4*)(rowb + (size_t)(tt + t) * XPN + g * 4);
            *(float4*)&xb[t][12 * (g >> 1) + 4 * (g & 1)] = v;
        }
        {   // stage dt/xs scalars: 16t x 16d
            size_t g = dbase + (size_t)(tt + st) * DI + sj;
            sdt[st][sj] = dt[g];
            sxs[st][sj] = xs[g];
        }
        __syncthreads();
        int nt = min(TT, t1 - tt);
        int k = 0;
        for (; k + 2 <= nt; k += 2) {
            float dva = sdt[k][jb],     xva = sxs[k][jb];
            float dvb = sdt[k + 1][jb], xvb = sxs[k + 1][jb];
            float4 v0 = *(const float4*)&xb[k][lo];
            float4 v1 = *(const float4*)&xb[k][lo + 4];
            float4 w0 = *(const float4*)&xb[k + 1][lo];
            float4 w1 = *(const float4*)&xb[k + 1][lo + 4];
            f32x2 Ba[4] = {{v0.x,v0.y},{v0.z,v0.w},{v1.x,v1.y},{v1.z,v1.w}};
            f32x2 Bb[4] = {{w0.x,w0.y},{w0.z,w0.w},{w1.x,w1.y},{w1.z,w1.w}};
            float ua = dva * xva, ub = dvb * xvb;
            S += dva + dvb;
            f32x2 ua2 = {ua, ua}, ub2 = {ub, ub};
            f32x2 dva2 = {dva, dva}, dvb2 = {dvb, dvb};
#pragma unroll
            for (int q = 0; q < 4; ++q) {
                f32x2 ga = dva2 * a2[q];
                f32x2 ea; ea[0] = fexp2(ga[0]); ea[1] = fexp2(ga[1]);
                h2[q] = h2[q] * ea + ua2 * Ba[q];
                f32x2 gb = dvb2 * a2[q];
                f32x2 eb; eb[0] = fexp2(gb[0]); eb[1] = fexp2(gb[1]);
                h2[q] = h2[q] * eb + ub2 * Bb[q];
            }
        }
        if (k < nt) {
            float dv = sdt[k][jb], xv = sxs[k][jb];
            float4 v0 = *(const float4*)&xb[k][lo];
            float4 v1 = *(const float4*)&xb[k][lo + 4];
            f32x2 Bv[4] = {{v0.x,v0.y},{v0.z,v0.w},{v1.x,v1.y},{v1.z,v1.w}};
            float u = dv * xv;
            S += dv;
            f32x2 u2 = {u, u}, dv2 = {dv, dv};
#pragma unroll
            for (int q = 0; q < 4; ++q) {
                f32x2 g = dv2 * a2[q];
                f32x2 e; e[0] = fexp2(g[0]); e[1] = fexp2(g[1]);
                h2[q] = h2[q] * e + u2 * Bv[q];
            }
        }
    }
    size_t base = ((size_t)hd * NC + c) * 128 + l;
#pragma unroll
    for (int q = 0; q < 4; ++q) {
        H[base + 32 * q]      = h2[q][0];
        H[base + 32 * q + 16] = h2[q][1];
    }
    if (l == 0) Sarr[(size_t)hd * NC + c] = S;
}

// ---------------- chunked scan pass 2: serial combine (in-place H -> h_start) ------
__global__ __launch_bounds__(128) void scan_combine_kernel(
    const float* __restrict__ Sarr, float* __restrict__ H,
    const float* __restrict__ A_log, float* __restrict__ Hfinal, int NC)
{
    int hd = blockIdx.x;
    int d = hd & 511;
    int n = threadIdx.x;
    float a = -__expf(A_log[d * NS + n]) * L2E;
    size_t base = (size_t)hd * NC * 128 + n;
    float h = 0.f;
    for (int c = 0; c < NC; ++c) {
        size_t off = base + (size_t)c * 128;
        float p = fexp2(a * Sarr[(size_t)hd * NC + c]);
        float hh = H[off];
        H[off] = h;                // h_start for chunk c (exclusive prefix)
        h = p * h + hh;
    }
    if (Hfinal) Hfinal[(size_t)hd * 128 + n] = h;
}

// ---------------- chunked scan pass 3: LDS-staged replay + emit gated y (bf16) ------
__global__ __launch_bounds__(256) void scan_emit_kernel(
    const float* __restrict__ dt, const float* __restrict__ xdbl,
    const float* __restrict__ xs, const float* __restrict__ xz,
    const float* __restrict__ A_log, const float* __restrict__ Hstart,
    const float* __restrict__ Dp,
    unsigned short* __restrict__ y, int T, int NC, int LC)
{
    __shared__ __align__(16) float xb[TT][RS2];   // B seg at 0, C seg at +196
    __shared__ float sdt[TT][16], sxs[TT][16], sz[TT][16];
    int b2 = blockIdx.x;
    int c = b2 % NC;
    int dpq = b2 / NC;
    int tid = threadIdx.x;
    int w = tid >> 6, lane = tid & 63;
    int sub = lane >> 4, l = lane & 15;
    int jb = w * 4 + sub;
    int hd = dpq * 16 + jb;
    int d = hd & 511;
    int half = (dpq * 16) >> 9;
    int d0 = (dpq * 16) & 511;
    f32x2 a2[4];
#pragma unroll
    for (int q = 0; q < 4; ++q) {
        a2[q][0] = -__expf(A_log[d * NS + 32 * q + l])      * L2E;
        a2[q][1] = -__expf(A_log[d * NS + 32 * q + 16 + l]) * L2E;
    }
    const float Dv = Dp[d];
    size_t base = ((size_t)hd * NC + c) * 128 + l;
    f32x2 h2[4];
#pragma unroll
    for (int q = 0; q < 4; ++q) {
        h2[q][0] = Hstart[base + 32 * q];
        h2[q][1] = Hstart[base + 32 * q + 16];
    }
    int t0 = c * LC, t1 = min(T, t0 + LC);
    const size_t dbase = (size_t)half * T * DI + d0;
    const float* rowb = xdbl + (size_t)half * T * XPN + 32;
    int st = tid >> 4, sj = tid & 15;
    size_t ybase = (size_t)half * T * DI + d;
    const int lo = 12 * l;
    for (int tt = t0; tt < t1; tt += TT) {
        __syncthreads();
        // stage B+C rows: 16t x 64 float4; per-seg chunked 12-dword per lane.
#pragma unroll
        for (int q = 0; q < 4; ++q) {
            int fi = q * 256 + tid;
            int t = fi >> 6, g = fi & 63;
            int seg = g >> 5, gl = g & 31;
            float4 v = *(const float4*)(rowb + (size_t)(tt + t) * XPN + g * 4);
            *(float4*)&xb[t][seg * 196 + 12 * (gl >> 1) + 4 * (gl & 1)] = v;
        }
        {   // stage dt/xs/silu(z) scalars
            size_t g = dbase + (size_t)(tt + st) * DI + sj;
            sdt[st][sj] = dt[g];
            sxs[st][sj] = xs[g];
            int tg = half ? (T - 1 - (tt + st)) : (tt + st);
            sz[st][sj] = xz[(size_t)tg * 1024 + 512 + d0 + sj];
        }
        __syncthreads();
        int nt = min(TT, t1 - tt);
        for (int k = 0; k + 2 <= nt; k += 2) {
            float dva = sdt[k][jb],     xva = sxs[k][jb];
            float dvb = sdt[k + 1][jb], xvb = sxs[k + 1][jb];
            float ga = sz[k][jb], gb = sz[k + 1][jb];
            float4 v0 = *(const float4*)&xb[k][lo];
            float4 v1 = *(const float4*)&xb[k][lo + 4];
            float4 c0 = *(const float4*)&xb[k][196 + lo];
            float4 c1 = *(const float4*)&xb[k][196 + lo + 4];
            float4 w0 = *(const float4*)&xb[k + 1][lo];
            float4 w1 = *(const float4*)&xb[k + 1][lo + 4];
            float4 e0 = *(const float4*)&xb[k + 1][196 + lo];
            float4 e1 = *(const float4*)&xb[k + 1][196 + lo + 4];
            f32x2 Ba[4] = {{v0.x,v0.y},{v0.z,v0.w},{v1.x,v1.y},{v1.z,v1.w}};
            f32x2 Ca[4] = {{c0.x,c0.y},{c0.z,c0.w},{c1.x,c1.y},{c1.z,c1.w}};
            f32x2 Bb[4] = {{w0.x,w0.y},{w0.z,w0.w},{w1.x,w1.y},{w1.z,w1.w}};
            f32x2 Cb[4] = {{e0.x,e0.y},{e0.z,e0.w},{e1.x,e1.y},{e1.z,e1.w}};
            float ua = dva * xva, ub = dvb * xvb;
            f32x2 ua2 = {ua, ua}, ub2 = {ub, ub};
            f32x2 dva2 = {dva, dva}, dvb2 = {dvb, dvb};
            f32x2 pa2 = {0.f, 0.f}, pb2 = {0.f, 0.f};
#pragma unroll
            for (int q = 0; q < 4; ++q) {
                f32x2 gaa = dva2 * a2[q];
                f32x2 ea; ea[0] = fexp2(gaa[0]); ea[1] = fexp2(gaa[1]);
                h2[q] = h2[q] * ea + ua2 * Ba[q];
                pa2 += h2[q] * Ca[q];
            }
#pragma unroll
            for (int q = 0; q < 4; ++q) {
                f32x2 gbb = dvb2 * a2[q];
                f32x2 eb; eb[0] = fexp2(gbb[0]); eb[1] = fexp2(gbb[1]);
                h2[q] = h2[q] * eb + ub2 * Bb[q];
                pb2 += h2[q] * Cb[q];
            }
            float pa = pa2[0] + pa2[1], pb = pb2[0] + pb2[1];
            pa += __shfl_xor(pa, 1, 64);  pb += __shfl_xor(pb, 1, 64);
            pa += __shfl_xor(pa, 2, 64);  pb += __shfl_xor(pb, 2, 64);
            pa += __shfl_xor(pa, 4, 64);  pb += __shfl_xor(pb, 4, 64);
            pa += __shfl_xor(pa, 8, 64);  pb += __shfl_xor(pb, 8, 64);
            if (l == 0) {
                y[ybase + (size_t)(tt + k) * DI]     = f2bf((pa + xva * Dv) * ga);
                y[ybase + (size_t)(tt + k + 1) * DI] = f2bf((pb + xvb * Dv) * gb);
            }
        }
    }
}

// ---------------- cross: last-step readout (permuted C layout) ----------------
__global__ __launch_bounds__(64) void cross_readout_kernel(
    const float* __restrict__ Hfinal, const float* __restrict__ xdbl,
    const float* __restrict__ xs, const float* __restrict__ xz,
    const float* __restrict__ Dp, float* __restrict__ ylast, int T)
{
    int hd = blockIdx.x;
    int half = hd >> 9, d = hd & 511;
    int lane = threadIdx.x;
    xdbl += (size_t)half * T * XPN;
    xs   += (size_t)half * T * DI;
    xz   += (size_t)half * T * 1024;
    float h0 = Hfinal[(size_t)hd * 128 + lane];          // state n = lane
    float h1 = Hfinal[(size_t)hd * 128 + 64 + lane];     // state n = 64+lane
    const float* xl = xdbl + (size_t)(T - 1) * XPN;
    int pos = 160 + (lane & 15) * 8 + (lane >> 4);
    float C0 = xl[pos];            // n = lane
    float C1 = xl[pos + 4];        // n = 64+lane
    float p = h0 * C0 + h1 * C1;
#pragma unroll
    for (int off = 32; off > 0; off >>= 1) p += __shfl_down(p, off, 64);
    if (lane == 0) {
        float xlast = xs[(size_t)(T - 1) * DI + d];
        float zl = xz[(size_t)(T - 1) * 1024 + 512 + d];
        ylast[half * DI + d] = (p + xlast * Dp[d]) * (zl * sigm(zl));
    }
}

// ---------------- row softmax + scatter into both cross sequences (bf16 SEQ) -------
__global__ __launch_bounds__(256) void softmax_scatter_kernel(
    const float* __restrict__ yo, unsigned short* __restrict__ seq, int T)
{
    __shared__ float sm[4];
    const int t = blockIdx.x, half = blockIdx.y, tid = threadIdx.x;
    const float* row = yo + (size_t)half * T * DI + (size_t)t * DI;
    float v0 = row[tid], v1 = row[tid + 256];
    float m = fmaxf(v0, v1);
#pragma unroll
    for (int o = 32; o > 0; o >>= 1) m = fmaxf(m, __shfl_xor(m, o, 64));
    if ((tid & 63) == 0) sm[tid >> 6] = m;
    __syncthreads();
    m = fmaxf(fmaxf(sm[0], sm[1]), fmaxf(sm[2], sm[3]));
    __syncthreads();
    float e0 = __expf(v0 - m), e1 = __expf(v1 - m);
    float s = e0 + e1;
#pragma unroll
    for (int o = 32; o > 0; o >>= 1) s += __shfl_xor(s, o, 64);
    if ((tid & 63) == 0) sm[tid >> 6] = s;
    __syncthreads();
    s = sm[0] + sm[1] + sm[2] + sm[3];
    float inv = 1.f / s;
    unsigned short b0 = f2bf(e0 * inv), b1 = f2bf(e1 * inv);
    unsigned short* seq_fi = seq;
    unsigned short* seq_if = seq + (size_t)TC * 1024;
    if (half == 0) {
        unsigned short* d1 = seq_fi + (size_t)t * 1024;
        unsigned short* d2 = seq_if + (size_t)t * 1024 + 512;
        d1[tid] = b0; d1[tid + 256] = b1;
        d2[tid] = b0; d2[tid + 256] = b1;
    } else {
        int tg = T - 1 - t;
        unsigned short* d1 = seq_fi + (size_t)tg * 1024 + 512;
        unsigned short* d2 = seq_if + (size_t)tg * 1024;
        d1[tid] = b0; d1[tid + 256] = b1;
        d2[tid] = b0; d2[tid + 256] = b1;
    }
}

// ---------------- cls-token rows of the two sequences (bf16) ----------------
__global__ __launch_bounds__(256) void cls_rows_kernel(
    const float* __restrict__ cls1, const float* __restrict__ cls2,
    unsigned short* __restrict__ seq)
{
    int i = blockIdx.x * 256 + threadIdx.x;   // 0..2047
    if (i < 1024)
        seq[(size_t)(TC - 1) * 1024 + i] = f2bf(cls1[i]);
    else
        seq[(size_t)TC * 1024 + (size_t)(TC - 1) * 1024 + (i - 1024)] = f2bf(cls2[i - 1024]);
}

// ---------------- vec [512] @ out_w [512,512] -> [512] ----------------
__global__ __launch_bounds__(256) void vecmat_kernel(
    const float* __restrict__ ylast, const float* __restrict__ Wout,
    float* __restrict__ olast)
{
    int half = blockIdx.y;
    int j = blockIdx.x * 256 + threadIdx.x;
    const float* v = ylast + half * DI;
    float acc = 0.f;
    for (int k = 0; k < DI; ++k) acc += v[k] * Wout[k * DI + j];
    olast[half * DI + j] = acc;
}

// ---------------- final classifier -> f32 [2] ----------------
__global__ __launch_bounds__(256) void final_kernel(
    const float* __restrict__ ol, const float* __restrict__ cw,
    const float* __restrict__ cb, float* __restrict__ out)
{
    __shared__ float s0[4], s1[4];
    int tid = threadIdx.x;
    float a0 = 0.f, a1 = 0.f;
    for (int j = tid; j < 1024; j += 256) {
        float v = ol[j];
        a0 += v * cw[2 * j];
        a1 += v * cw[2 * j + 1];
    }
#pragma unroll
    for (int o = 32; o > 0; o >>= 1) { a0 += __shfl_xor(a0, o, 64); a1 += __shfl_xor(a1, o, 64); }
    if ((tid & 63) == 0) { s0[tid >> 6] = a0; s1[tid >> 6] = a1; }
    __syncthreads();
    if (tid == 0) {
        out[0] = s0[0] + s0[1] + s0[2] + s0[3] + cb[0];
        out[1] = s1[0] + s1[1] + s1[2] + s1[3] + cb[1];
    }
}

extern "C" void kernel_launch(void* const* d_in, const int* in_sizes, int n_in,
                              void* d_out, int out_size, void* d_ws, size_t ws_size,
                              hipStream_t stream)
{
    float* out = (float*)d_out;
    float* ws = (float*)d_ws;

    // ---- input-order resolution via in_sizes (dict vs signature order) ----
    static const int sig_map[25] = {0,1,2,3,4,23,24,5,6,7,8,9,10,11,12,13,
                                    14,15,16,17,18,19,20,21,22};
    int idx[25];
    bool dict_order = (n_in >= 7 && in_sizes[6] == 2);
    for (int i = 0; i < 25; ++i) idx[i] = dict_order ? i : sig_map[i];

    // ---- aliased workspace layout (f32 elements) ----
    const size_t A0 = 0;         // x(bf16) -> dt_simple -> yo -> XSC         (2,098,176)
    const size_t B0 = 2098176;   // f(bf16) / S_S -> XDC                      (1,180,224)
    const size_t C0 = 3278400;   // XZS / XZC (XZC spans ..7,474,752)         (2,097,152)
    const size_t D0 = 5375552;   // XS                                        (2,097,152)
    const size_t E0 = 7472704;   // XDBL                                      (1,179,648)
    const size_t F0 = 8652352;   // y(bf16) / YS                              (2,097,152)
    const size_t G0 = 10749504;  // H_S (NC=32, 4,194,304) -> SEQ(bf16)       (4,196,352)
    const size_t YL0 = 14945856; // 1024
    const size_t OL0 = 14946880; // 1024
    const size_t DT_S = A0;
    const size_t S_S  = B0 + 524288;     // after bf16 f (f = 1M ushorts = 524,288 fl)
    const size_t H_S  = G0;              // 1024*32*128 = 4,194,304
    const size_t DT_C = 7474752;
    const size_t H_C  = 9572928;         // 1024*33*128 = 4,325,376 -> ends 13,898,304
    const size_t S_C  = 13898304;        // 1024*33 = 33,792
    const size_t HFIN = 14029376;        // 131,072
    size_t o = 14947904;
    const size_t P_FEATW = o; o += 524288;   // bf16 Wt[512][1024]
    const size_t P_FEATB = o; o += 512;
    const size_t P_CLS1  = o; o += 1024;
    const size_t P_CLS2  = o; o += 1024;
    const size_t P_CLSW  = o; o += 2048;
    const size_t P_CLSB  = o; o += 4;
    const size_t P_MINW  = o; o += 524288;   // bf16 Wt[1024][512]
    const size_t P_MCW   = o; o += 2048;
    const size_t P_MCB   = o; o += 512;
    const size_t P_MXP   = o; o += 147456;   // bf16 Wt[288][512]
    const size_t P_MDTW  = o; o += 16384;
    const size_t P_MDTB  = o; o += 512;
    const size_t P_MAL   = o; o += 65536;
    const size_t P_MD    = o; o += 512;
    const size_t P_MOW   = o; o += 262144;   // bf16 Wt[512][512]
    const size_t P_CINW  = o; o += 1048576;  // bf16 Wt[1024][1024]
    const size_t P_CCW   = o; o += 2048;
    const size_t P_CCB   = o; o += 512;
    const size_t P_CXP   = o; o += 147456;   // bf16 Wt[288][512]
    const size_t P_CDTW  = o; o += 16384;
    const size_t P_CDTB  = o; o += 512;
    const size_t P_CAL   = o; o += 65536;
    const size_t P_CD    = o; o += 512;
    const size_t P_COW   = o; o += 262144;
    const size_t OFF_FLAG = o;               // 1 int

    int* flagp = (int*)(ws + OFF_FLAG);
    unsigned short* XB   = (unsigned short*)(ws + A0);
    unsigned short* FB   = (unsigned short*)(ws + B0);
    unsigned short* YB   = (unsigned short*)(ws + F0);
    unsigned short* SEQB = (unsigned short*)(ws + G0);
    unsigned short* WT_FEATW = (unsigned short*)(ws + P_FEATW);
    unsigned short* WT_MINW  = (unsigned short*)(ws + P_MINW);
    unsigned short* WT_MXP   = (unsigned short*)(ws + P_MXP);
    unsigned short* WT_MOW   = (unsigned short*)(ws + P_MOW);
    unsigned short* WT_CINW  = (unsigned short*)(ws + P_CINW);
    unsigned short* WT_CXP   = (unsigned short*)(ws + P_CXP);

    // 0) detect input dtype
    detect_kernel<<<1, 256, 0, stream>>>((const unsigned short*)d_in[idx[0]], flagp);

    // 1) widen non-GEMM inputs (18 plain) + x->bf16 + 6 GEMM weights (bf16, transposed)
    WDT tab;
    const int lg[18]  = {2,3,4,5,6,8,9,11,12,13,14,17,18,20,21,22,23,24};
    const int nsl[25] = {2097152, 524288, 512, 1024, 1024, 2048, 2,
                         524288, 2048, 512, 147456, 16384, 512, 65536, 512, 262144,
                         1048576, 2048, 512, 147456, 16384, 512, 65536, 512, 262144};
    float* dstl[25] = {
        nullptr, nullptr, ws + P_FEATB, ws + P_CLS1, ws + P_CLS2,
        ws + P_CLSW, ws + P_CLSB,
        nullptr, ws + P_MCW, ws + P_MCB, nullptr, ws + P_MDTW, ws + P_MDTB,
        ws + P_MAL, ws + P_MD, nullptr,
        nullptr, ws + P_CCW, ws + P_CCB, nullptr, ws + P_CDTW, ws + P_CDTB,
        ws + P_CAL, ws + P_CD, ws + P_COW};
    for (int i = 0; i < 18; ++i) {
        int s = lg[i];
        tab.e[i].src = d_in[idx[s]];
        tab.e[i].dst = dstl[s];
        tab.e[i].n = nsl[s];
    }
    widen_all_kernel<<<dim3(128, 18), 256, 0, stream>>>(tab, flagp);
    x2bf_kernel<<<8192, 256, 0, stream>>>(d_in[idx[0]], XB, 2097152, flagp);
    wt_plain_kernel<<<dim3(32, 16), 256, 0, stream>>>(d_in[idx[1]],  WT_FEATW, 1024, 512,  flagp);
    wt_plain_kernel<<<dim3(16, 32), 256, 0, stream>>>(d_in[idx[7]],  WT_MINW,  512,  1024, flagp);
    wt_plain_kernel<<<dim3(16, 16), 256, 0, stream>>>(d_in[idx[15]], WT_MOW,   512,  512,  flagp);
    wt_plain_kernel<<<dim3(32, 32), 256, 0, stream>>>(d_in[idx[16]], WT_CINW,  1024, 1024, flagp);
    wt_xproj_kernel<<<576, 256, 0, stream>>>(d_in[idx[10]], WT_MXP, flagp);
    wt_xproj_kernel<<<576, 256, 0, stream>>>(d_in[idx[19]], WT_CXP, flagp);

    // 2) f = relu(x @ feat_w + feat_b)        A(bf16) -> B(bf16)
    gemm_mfma_kernel<<<dim3(32, 8, 1), 256, 0, stream>>>(XB, 1024, 0, WT_FEATW, 512, 1024,
                                                         ws + P_FEATB, FB, 512, 0,
                                                         2048, 1, 1, 1);
    // 3) xz = f @ m_in_w                      B(bf16) -> C(f32)
    gemm_mfma_kernel<<<dim3(32, 16, 1), 256, 0, stream>>>(FB, 512, 0, WT_MINW, 1024, 512,
                                                          nullptr, ws + C0, 1024, 0,
                                                          2048, 0, 1, 0);
    // 4) conv+silu both dirs + fused in-place z-silu    C -> D (+C z-cols)
    conv_silu_kernel<<<8192, 256, 0, stream>>>(ws + C0, 1024, 0, ws + P_MCW, ws + P_MCB,
                                               ws + D0, 2048, 1, ws + C0);
    // 5) x_dbl = xs @ m_xproj_w (permuted)    D(f32) -> E(f32)
    gemm_mfma_kernel<<<dim3(32, 5, 2), 256, 0, stream>>>(ws + D0, 512, 2048LL * 512, WT_MXP,
                                                         288, 512, nullptr, ws + E0, 288,
                                                         2048LL * 288, 2048, 0, 0, 0);
    // 5b) dt = softplus(x_dbl[:, :32] @ dt_w + dt_b)   E -> DT_S (A)
    dt_kernel<<<8192, 256, 0, stream>>>(ws + E0, ws + P_MDTW, ws + P_MDTB, ws + DT_S, 2048);
    // 6) chunked scan: T=2048, 32 chunks x 64 (64 dpq x 32 c = 2048 blocks)
    scan_part1_kernel<<<2048, 256, 0, stream>>>(ws + DT_S, ws + E0, ws + D0, ws + P_MAL,
                                                ws + S_S, ws + H_S, 2048, 32, 64);
    scan_combine_kernel<<<1024, 128, 0, stream>>>(ws + S_S, ws + H_S, ws + P_MAL, nullptr, 32);
    // 6b) emit with fused gating, bf16 y out
    scan_emit_kernel<<<2048, 256, 0, stream>>>(ws + DT_S, ws + E0, ws + D0, ws + C0,
                                               ws + P_MAL, ws + H_S, ws + P_MD,
                                               YB, 2048, 32, 64);
    // 7) yo = y @ m_out_w                     F(bf16) -> A(f32 yo)
    gemm_mfma_kernel<<<dim3(32, 8, 2), 256, 0, stream>>>(YB, 512, 2048LL * 512, WT_MOW,
                                                         512, 512, nullptr, ws + A0, 512,
                                                         2048LL * 512, 2048, 0, 1, 0);
    // 8) cls-token rows into SEQ (bf16)       P -> G
    cls_rows_kernel<<<8, 256, 0, stream>>>(ws + P_CLS1, ws + P_CLS2, SEQB);
    // 9) softmax + scatter (bf16 SEQ)         A -> G
    softmax_scatter_kernel<<<dim3(2048, 2), 256, 0, stream>>>(ws + A0, SEQB, 2048);
    // 10) cross in-proj                       G(bf16) -> C(f32 XZC)
    gemm_mfma_kernel<<<dim3(33, 16, 2), 256, 0, stream>>>(SEQB, 1024, 2049LL * 1024, WT_CINW,
                                                          1024, 1024, nullptr, ws + C0, 1024,
                                                          2049LL * 1024, 2049, 0, 1, 0);
    // 11) cross conv+silu (no fused z)        C -> A (XSC)
    conv_silu_kernel<<<8196, 256, 0, stream>>>(ws + C0, 1024, 2049LL * 1024, ws + P_CCW,
                                               ws + P_CCB, ws + A0, 2049, 0, nullptr);
    // 12) cross x_dbl (permuted)              A(f32) -> B(f32 XDC)
    gemm_mfma_kernel<<<dim3(33, 5, 2), 256, 0, stream>>>(ws + A0, 512, 2049LL * 512, WT_CXP,
                                                         288, 512, nullptr, ws + B0, 288,
                                                         2049LL * 288, 2049, 0, 0, 0);
    // 12b) cross dt                           B -> DT_C
    dt_kernel<<<8196, 256, 0, stream>>>(ws + B0, ws + P_CDTW, ws + P_CDTB, ws + DT_C, 2049);
    // 13) cross chunked scan: T=2049, 33 chunks x 64 (64 dpq x 33 c = 2112 blocks)
    scan_part1_kernel<<<2112, 256, 0, stream>>>(ws + DT_C, ws + B0, ws + A0, ws + P_CAL,
                                                ws + S_C, ws + H_C, 2049, 33, 64);
    scan_combine_kernel<<<1024, 128, 0, stream>>>(ws + S_C, ws + H_C, ws + P_CAL, ws + HFIN, 33);
    cross_readout_kernel<<<1024, 64, 0, stream>>>(ws + HFIN, ws + B0, ws + A0, ws + C0,
                                                  ws + P_CD, ws + YL0, 2049);
    // 14) out-projection of last rows         YL -> OL
    vecmat_kernel<<<dim3(2, 2), 256, 0, stream>>>(ws + YL0, ws + P_COW, ws + OL0);
    // 15) classifier                          OL -> out (f32)
    final_kernel<<<1, 256, 0, stream>>>(ws + OL0, ws + P_CLSW, ws + P_CLSB, out);
}